// Round 10
// baseline (589.171 us; speedup 1.0000x reference)
//
#include <hip/hip_runtime.h>

#define B_    256
#define L_    200
#define EMB_  128
#define HD_   64
#define HCN_  1000
#define POI_  20000
#define EPS_  1e-8f
#define CP    224          // padded L for c / ut k-dim (7 chunks of 32)
#define UNR   208          // umap-native rows (l), rows 200..207 zero

// power-of-2 pre-scales keep fp16 second-splits in the normal range
#define CSC   16384.0f     // c scale (2^14)
#define USC   256.0f       // umap scale (2^8)
#define VSC   1024.0f      // v scale (2^10)
#define SV_DESC (1.0f / (CSC * USC))   // 2^-22, exact
#define UV_DESC (1.0f / (VSC * USC))   // 2^-18, exact

typedef _Float16 half8 __attribute__((ext_vector_type(8)));
typedef __bf16  bf16x8 __attribute__((ext_vector_type(8)));
typedef float   f32x4  __attribute__((ext_vector_type(4)));
typedef float   f32x16 __attribute__((ext_vector_type(16)));

__device__ __forceinline__ unsigned short f2bf(float f) {
  union { float f; unsigned int u; } v; v.f = f;
  unsigned int r = (v.u + 0x7FFFu + ((v.u >> 16) & 1u)) >> 16;  // RNE
  return (unsigned short)r;
}
// 2-way fp16 split of a PRE-SCALED value: x ~= s1+s2 to ~2^-22 relative
__device__ __forceinline__ void split2h(float x, _Float16& s1, _Float16& s2) {
  s1 = (_Float16)x;
  s2 = (_Float16)(x - (float)s1);
}

// 4-pass split product (keeps all cross terms; small-first accumulation)
#define FOURPASS(acc, A1f, A2f, B1f, B2f)                                  \
  acc = __builtin_amdgcn_mfma_f32_16x16x32_f16(A2f, B2f, acc, 0, 0, 0);    \
  acc = __builtin_amdgcn_mfma_f32_16x16x32_f16(A2f, B1f, acc, 0, 0, 0);    \
  acc = __builtin_amdgcn_mfma_f32_16x16x32_f16(A1f, B2f, acc, 0, 0, 0);    \
  acc = __builtin_amdgcn_mfma_f32_16x16x32_f16(A1f, B1f, acc, 0, 0, 0);

// ---------------------------------------------------------------------------
// k_umap: u_map[b,l,:] = u[b,l,:] @ l_map_h  (fp32 — routing precision source)
__global__ __launch_bounds__(256) void k_umap(const float* __restrict__ u,
                                              const float* __restrict__ lmap,
                                              float* __restrict__ umap) {
  __shared__ __align__(16) float lm[EMB_ * HD_];   // 32 KB
  for (int i = threadIdx.x; i < EMB_ * HD_; i += 256) lm[i] = lmap[i];
  __syncthreads();
  const int wave = threadIdx.x >> 6, lane = threadIdx.x & 63;
  const int wid = blockIdx.x * 4 + wave;
  for (int row = wid; row < B_ * L_; row += 3200) {
    const float* ur = u + (size_t)row * EMB_;
    float a0 = ur[lane];
    float a1 = ur[lane + 64];
    float acc = 0.f;
#pragma unroll
    for (int k = 0; k < 64; ++k)
      acc = fmaf(__shfl(a0, k), lm[k * HD_ + lane], acc);
#pragma unroll
    for (int k = 0; k < 64; ++k)
      acc = fmaf(__shfl(a1, k), lm[(k + 64) * HD_ + lane], acc);
    umap[(size_t)row * HD_ + lane] = acc;
  }
}

// ---------------------------------------------------------------------------
// k_prep2: umap[b] fp32 -> fp16 2-splits of (umap*USC), native [b][208][64]
// (rows 200..207 zero) and transposed [b][64][224] (cols 200..223 zero).
__global__ __launch_bounds__(256) void k_prep2(const float* __restrict__ umap,
    _Float16* __restrict__ un1, _Float16* __restrict__ un2,
    _Float16* __restrict__ ut1, _Float16* __restrict__ ut2) {
  __shared__ __align__(16) float us[CP][68];   // 60.9 KB
  const int b = blockIdx.x;
  const float* ub = umap + (size_t)b * L_ * HD_;
  for (int i = threadIdx.x; i < CP * HD_; i += 256) {
    int l = i >> 6, d = i & 63;
    us[l][d] = (l < L_) ? ub[l * HD_ + d] * USC : 0.f;
  }
  __syncthreads();
  // native: (row 208, oct 8)
  for (int s = threadIdx.x; s < UNR * 8; s += 256) {
    int row = s >> 3, oct = s & 7;
    _Float16 t1[8], t2[8];
#pragma unroll
    for (int j = 0; j < 8; ++j) split2h(us[row][oct * 8 + j], t1[j], t2[j]);
    size_t dst = ((size_t)b * UNR + row) * HD_ + oct * 8;
    *(uint4*)&un1[dst] = *(uint4*)t1;
    *(uint4*)&un2[dst] = *(uint4*)t2;
  }
  // transposed: (d 64, l-oct 28)
  for (int s = threadIdx.x; s < HD_ * 28; s += 256) {
    int d = s / 28, lo8 = s % 28;
    _Float16 t1[8], t2[8];
#pragma unroll
    for (int j = 0; j < 8; ++j) split2h(us[lo8 * 8 + j][d], t1[j], t2[j]);
    size_t dst = ((size_t)b * HD_ + d) * CP + lo8 * 8;
    *(uint4*)&ut1[dst] = *(uint4*)t1;
    *(uint4*)&ut2[dst] = *(uint4*)t2;
  }
}

// ---------------------------------------------------------------------------
// k_softmax2: (SUM) fold 8 partial slabs into b[row,:] (write back, zero the
// slabs); then c[row,:] = softmax(b[row,:]) -> fp16 2-splits of (c*CSC),
// [1024][224]; rows 1000..1023 and cols 200..223 exact zero.
template<int SUM>
__global__ __launch_bounds__(256) void k_softmax2(float* __restrict__ bl,
    float* __restrict__ part,
    _Float16* __restrict__ c1, _Float16* __restrict__ c2) {
  const int wave = threadIdx.x >> 6, lane = threadIdx.x & 63;
  const int row = blockIdx.x * 4 + wave;                 // 0..1023
  const size_t rb = (size_t)row * CP;
  if (row >= HCN_) {
    c1[rb + lane] = (_Float16)0.f;       c2[rb + lane] = (_Float16)0.f;
    c1[rb + lane + 64] = (_Float16)0.f;  c2[rb + lane + 64] = (_Float16)0.f;
    c1[rb + lane + 128] = (_Float16)0.f; c2[rb + lane + 128] = (_Float16)0.f;
    if (lane < 32) { c1[rb + 192 + lane] = (_Float16)0.f; c2[rb + 192 + lane] = (_Float16)0.f; }
    return;
  }
  float* br = bl + (size_t)row * L_;
  float x0 = br[lane];
  float x1 = br[lane + 64];
  float x2 = br[lane + 128];
  float x3 = (lane < 8) ? br[lane + 192] : -3.0e38f;
  if (SUM) {
#pragma unroll
    for (int s = 0; s < 8; ++s) {
      float* p = part + ((size_t)s * HCN_ + row) * L_;
      x0 += p[lane];
      x1 += p[lane + 64];
      x2 += p[lane + 128];
      if (lane < 8) x3 += p[lane + 192];
      // zero the slab for the next k_iter (slab state self-restoring)
      p[lane] = 0.f; p[lane + 64] = 0.f; p[lane + 128] = 0.f;
      if (lane < 8) p[lane + 192] = 0.f;
    }
    br[lane] = x0; br[lane + 64] = x1; br[lane + 128] = x2;
    if (lane < 8) br[lane + 192] = x3;
  }
  float m = fmaxf(fmaxf(x0, x1), fmaxf(x2, x3));
#pragma unroll
  for (int off = 32; off; off >>= 1) m = fmaxf(m, __shfl_xor(m, off));
  float e0 = expf(x0 - m), e1 = expf(x1 - m), e2 = expf(x2 - m);
  float e3 = (lane < 8) ? expf(x3 - m) : 0.f;
  float ssum = e0 + e1 + e2 + e3;
#pragma unroll
  for (int off = 32; off; off >>= 1) ssum += __shfl_xor(ssum, off);
  float inv = CSC / ssum;
  _Float16 s1, s2;
  split2h(e0 * inv, s1, s2); c1[rb + lane] = s1;       c2[rb + lane] = s2;
  split2h(e1 * inv, s1, s2); c1[rb + lane + 64] = s1;  c2[rb + lane + 64] = s2;
  split2h(e2 * inv, s1, s2); c1[rb + lane + 128] = s1; c2[rb + lane + 128] = s2;
  if (lane < 8) {
    split2h(e3 * inv, s1, s2); c1[rb + 192 + lane] = s1; c2[rb + 192 + lane] = s2;
  } else if (lane < 32) {
    c1[rb + 192 + lane] = (_Float16)0.f; c2[rb + 192 + lane] = (_Float16)0.f;
  }
}

// ---------------------------------------------------------------------------
// k_iter: fused routing iteration, fp16 2-split / 4-pass, pre-scaled.
// Per block: 4 batches x 64 h-rows. Async-staged LDS operands (T14: global->
// reg loads issued before MFMA/squash, reg->LDS writes after).
// Grid 1024, decode xcd=id&7, ht=(id>>3)&15, bh=(id>>7)&1, bgHi=(id>>8)&3,
// bg=xcd+8*bgHi: all blocks of one bg share the XCD (operand L2 locality);
// UV partial slab part[xcd] is XCD-local. 3 blocks/CU resident.
// HOUT writes h directly as padded bf16 [256][1024].
template<int UV, int HOUT>
__global__ __launch_bounds__(256, 3) void k_iter(
    const _Float16* __restrict__ c1p, const _Float16* __restrict__ c2p,
    const _Float16* __restrict__ un1, const _Float16* __restrict__ un2,
    const _Float16* __restrict__ ut1, const _Float16* __restrict__ ut2,
    const float* __restrict__ wdim, const float* __restrict__ bdim,
    float* __restrict__ part, unsigned short* __restrict__ hb) {
  // union region: ut_s [2][2][64][40] (20,480 B) / un_s [2][208][40] (33,280 B)
  __shared__ __align__(16) _Float16 smem[16640];
  __shared__ __align__(16) _Float16 v_s[2][64][72];   // 18,432 B (split-indexed)
  typedef _Float16 (*UTarr)[2][64][40];
  typedef _Float16 (*UNarr)[208][40];
  UTarr UT = reinterpret_cast<UTarr>(smem);
  UNarr UN = reinterpret_cast<UNarr>(smem);

  const int id = blockIdx.x;
  const int xcd = id & 7;
  const int ht  = (id >> 3) & 15;
  const int bh  = (id >> 7) & 1;
  const int bgH = (id >> 8) & 3;
  const int bg  = xcd + (bgH << 3);             // bg%8 == id%8 (XCD pin)
  const int h0 = ht * 64;
  const int b0 = bg * 8 + bh * 4;
  const int tid = threadIdx.x;
  const int wave = tid >> 6, lane = tid & 63;
  const int l15 = lane & 15, oc = lane >> 4;
  const int rowA = h0 + wave * 16 + l15;     // A-frag row (c row / v row)
  const int rowC = h0 + wave * 16 + oc * 4;  // C/D row base (+r)

  // async-stage registers
  uint4 rA, rB;          // UT chunk (2 splits)
  uint4 rUN[2][4];       // UN half  (2 splits x 4 slots)

#define LD_UT(cck) {                                                           \
    const int d_ = tid >> 2, q_ = tid & 3;                                     \
    const size_t so_ = ((size_t)b * HD_ + d_) * CP + (cck) * 32 + q_ * 8;      \
    rA = *(const uint4*)&ut1[so_];                                             \
    rB = *(const uint4*)&ut2[so_];                                             \
  }
#define ST_UT(bf) {                                                            \
    const int d_ = tid >> 2, q_ = tid & 3;                                     \
    *(uint4*)&UT[bf][0][d_][q_ * 8] = rA;                                      \
    *(uint4*)&UT[bf][1][d_][q_ * 8] = rB;                                      \
  }
#define LD_UN(half_) {                                                         \
    _Pragma("unroll")                                                          \
    for (int j_ = 0; j_ < 4; ++j_) {                                           \
      int t_ = tid + 256 * j_;                                                 \
      if (t_ < 832) {                                                          \
        int row_ = t_ >> 2, q_ = t_ & 3;                                       \
        const size_t so_ = ((size_t)b * UNR + row_) * HD_ + (half_) * 32 + q_ * 8; \
        rUN[0][j_] = *(const uint4*)&un1[so_];                                 \
        rUN[1][j_] = *(const uint4*)&un2[so_];                                 \
      } } }
#define ST_UN() {                                                              \
    _Pragma("unroll")                                                          \
    for (int j_ = 0; j_ < 4; ++j_) {                                           \
      int t_ = tid + 256 * j_;                                                 \
      if (t_ < 832) {                                                          \
        int row_ = t_ >> 2, q_ = t_ & 3;                                       \
        *(uint4*)&UN[0][row_][q_ * 8] = rUN[0][j_];                            \
        *(uint4*)&UN[1][row_][q_ * 8] = rUN[1][j_];                            \
      } } }

  // hoisted A fragments (c rows; invariant over the batches)
  half8 a_f[7][2];
#pragma unroll
  for (int ck = 0; ck < 7; ++ck) {
    const size_t off = (size_t)rowA * CP + ck * 32 + oc * 8;
    a_f[ck][0] = *(const half8*)&c1p[off];
    a_f[ck][1] = *(const half8*)&c2p[off];
  }

  f32x4 acc_uv[13];
  if (UV) {
#pragma unroll
    for (int nt = 0; nt < 13; ++nt) acc_uv[nt] = (f32x4){0.f, 0.f, 0.f, 0.f};
  }
  float wd[4] = {0.f, 0.f, 0.f, 0.f};
  float bd = 0.f;
  if (HOUT) {
#pragma unroll
    for (int nt = 0; nt < 4; ++nt) wd[nt] = wdim[nt * 16 + l15];
    bd = bdim[0];
  }

  for (int bi = 0; bi < 4; ++bi) {
    const int b = b0 + bi;
    // ---------------- SV: s = c @ umap[b] (scaled 2^22) ----------------
    f32x4 acc_s[4];
#pragma unroll
    for (int nt = 0; nt < 4; ++nt) acc_s[nt] = (f32x4){0.f, 0.f, 0.f, 0.f};
    LD_UT(0);
    ST_UT(0);
    __syncthreads();
#pragma unroll
    for (int ck = 0; ck < 7; ++ck) {
      if (ck < 6) LD_UT(ck + 1);          // loads issue (vmcnt), no wait yet
      const int cb = ck & 1;
#pragma unroll
      for (int nt = 0; nt < 4; ++nt) {
        const half8 b1 = *(const half8*)&UT[cb][0][nt * 16 + l15][oc * 8];
        const half8 b2 = *(const half8*)&UT[cb][1][nt * 16 + l15][oc * 8];
        FOURPASS(acc_s[nt], a_f[ck][0], a_f[ck][1], b1, b2);
      }
      if (ck < 6) {
        ST_UT((ck + 1) & 1);              // load-wait lands after MFMA burst
        __syncthreads();
      }
    }
    // issue UN half-0 loads early (hide under squash VALU + v_s stores)
    if (UV) LD_UN(0);
    // ---------------- squash (in-register, descaled) ----------------
    float xdesc[4][4];   // [nt][r]
#pragma unroll
    for (int nt = 0; nt < 4; ++nt)
#pragma unroll
      for (int r = 0; r < 4; ++r) xdesc[nt][r] = acc_s[nt][r] * SV_DESC;
    float gg[4], hq[4];
#pragma unroll
    for (int r = 0; r < 4; ++r) {
      float sq = 0.f, hpp = 0.f;
#pragma unroll
      for (int nt = 0; nt < 4; ++nt) {
        float x = xdesc[nt][r];
        sq += x * x;
        if (HOUT) hpp += x * wd[nt];
      }
#pragma unroll
      for (int off = 8; off; off >>= 1) {
        sq += __shfl_xor(sq, off);
        if (HOUT) hpp += __shfl_xor(hpp, off);
      }
      gg[r] = sq / ((1.f + sq) * sqrtf(sq + EPS_));
      if (HOUT) hq[r] = gg[r] * hpp + bd;
    }
    if (HOUT && l15 == 0) {
      // padded bf16 h write: rows >= 1000 exact zero (rowC is 4-aligned)
      ushort4 hv4;
      if (rowC < HCN_) {
        hv4.x = f2bf(hq[0]); hv4.y = f2bf(hq[1]);
        hv4.z = f2bf(hq[2]); hv4.w = f2bf(hq[3]);
      } else {
        hv4.x = hv4.y = hv4.z = hv4.w = 0;
      }
      *(ushort4*)&hb[(size_t)b * 1024 + rowC] = hv4;
    }
    // ---------------- UV: acc_uv += v @ umap[b]^T ----------------
    if (UV) {
#pragma unroll
      for (int nt = 0; nt < 4; ++nt)
#pragma unroll
        for (int r = 0; r < 4; ++r) {
          _Float16 s1, s2;
          split2h(VSC * gg[r] * xdesc[nt][r], s1, s2);
          const int vr = wave * 16 + oc * 4 + r, vc = nt * 16 + l15;
          v_s[0][vr][vc] = s1; v_s[1][vr][vc] = s2;
        }
      __syncthreads();                    // A: v_s ready; SV UT reads done
      ST_UN();                            // half-0 regs -> LDS
      LD_UN(1);                           // issue half-1 loads
      __syncthreads();                    // B: UN half-0 ready
      {
        const half8 av1 = *(const half8*)&v_s[0][wave * 16 + l15][oc * 8];
        const half8 av2 = *(const half8*)&v_s[1][wave * 16 + l15][oc * 8];
#pragma unroll
        for (int nt = 0; nt < 13; ++nt) {
          const half8 b1 = *(const half8*)&UN[0][nt * 16 + l15][oc * 8];
          const half8 b2 = *(const half8*)&UN[1][nt * 16 + l15][oc * 8];
          FOURPASS(acc_uv[nt], av1, av2, b1, b2);
        }
      }
      __syncthreads();                    // C: UN half-0 consumed
      ST_UN();                            // half-1 regs -> LDS
      __syncthreads();                    // D: UN half-1 ready
      {
        const half8 av1 = *(const half8*)&v_s[0][wave * 16 + l15][32 + oc * 8];
        const half8 av2 = *(const half8*)&v_s[1][wave * 16 + l15][32 + oc * 8];
#pragma unroll
        for (int nt = 0; nt < 13; ++nt) {
          const half8 b1 = *(const half8*)&UN[0][nt * 16 + l15][oc * 8];
          const half8 b2 = *(const half8*)&UN[1][nt * 16 + l15][oc * 8];
          FOURPASS(acc_uv[nt], av1, av2, b1, b2);
        }
      }
      __syncthreads();                    // E: UN consumed; next batch may stage
    } else {
      __syncthreads();                    // protect UT buf0 for next batch
    }
  }
  if (UV) {
    // XCD-local partial slab (slab index = xcd = id%8)
    float* pp = part + (size_t)xcd * HCN_ * L_;
#pragma unroll
    for (int nt = 0; nt < 13; ++nt)
#pragma unroll
      for (int r = 0; r < 4; ++r) {
        const int row = rowC + r, l = nt * 16 + l15;
        if (row < HCN_ && l < L_)
          atomicAdd(&pp[(size_t)row * L_ + l], acc_uv[nt][r] * UV_DESC);
      }
  }
#undef LD_UT
#undef ST_UT
#undef LD_UN
#undef ST_UN
}

// ---------------------------------------------------------------------------
// k_out_mfma: out[b,p] = sum_h h[b,h]*w_part[p,h] + b_part[p]  via bf16 MFMA.
#define KPAD 1024
#define LPITCH 72
__global__ __launch_bounds__(512) void k_out_mfma(const unsigned short* __restrict__ hb,
                                                  const float* __restrict__ wpart,
                                                  const float* __restrict__ bpart,
                                                  float* __restrict__ out) {
  __shared__ __align__(16) unsigned short w_lds[128 * LPITCH];  // 18432 B
  __shared__ __align__(16) unsigned short h_lds[128 * LPITCH];  // 18432 B
  const int p0 = blockIdx.x * 128;
  const int b0 = blockIdx.y * 128;
  const int t = threadIdx.x;
  const int wave = t >> 6, lane = t & 63;
  const int nt = wave & 3, mh = wave >> 2;
  const int l31 = lane & 31, lhi = lane >> 5;

  f32x16 acc0 = {};
  f32x16 acc1 = {};

  const int wrow = t >> 2;
  const int wq0  = (t & 3) * 4;
  int prow = p0 + wrow; if (prow > POI_ - 1) prow = POI_ - 1;
  const float* wrp = wpart + (size_t)prow * HCN_;

  for (int ch = 0; ch < 16; ++ch) {
    const int k0 = ch * 64;
    __syncthreads();
#pragma unroll
    for (int qq = 0; qq < 4; ++qq) {
      const int q = wq0 + qq;
      float4 wv;
      if (k0 + q * 4 + 3 < HCN_) {
        wv = *(const float4*)(wrp + k0 + q * 4);
      } else {
        float x0 = (k0 + q * 4 + 0 < HCN_) ? wrp[k0 + q * 4 + 0] : 0.f;
        float x1 = (k0 + q * 4 + 1 < HCN_) ? wrp[k0 + q * 4 + 1] : 0.f;
        float x2 = (k0 + q * 4 + 2 < HCN_) ? wrp[k0 + q * 4 + 2] : 0.f;
        float x3 = (k0 + q * 4 + 3 < HCN_) ? wrp[k0 + q * 4 + 3] : 0.f;
        wv = make_float4(x0, x1, x2, x3);
      }
      ushort4 bv;
      bv.x = f2bf(wv.x); bv.y = f2bf(wv.y); bv.z = f2bf(wv.z); bv.w = f2bf(wv.w);
      *(ushort4*)&w_lds[wrow * LPITCH + q * 4] = bv;
    }
#pragma unroll
    for (int n = 0; n < 2; ++n) {
      const int u = t + n * 512;
      const int hrow = u >> 3, hc = u & 7;
      const uint4 hv = *(const uint4*)(hb + (size_t)(b0 + hrow) * KPAD + k0 + hc * 8);
      *(uint4*)&h_lds[hrow * LPITCH + hc * 8] = hv;
    }
    __syncthreads();
#pragma unroll
    for (int ks = 0; ks < 4; ++ks) {
      const int kc = ks * 16 + lhi * 8;
      bf16x8 bfr = *(const bf16x8*)&w_lds[(nt * 32 + l31) * LPITCH + kc];
      bf16x8 a0  = *(const bf16x8*)&h_lds[(mh * 64 + 0 * 32 + l31) * LPITCH + kc];
      bf16x8 a1  = *(const bf16x8*)&h_lds[(mh * 64 + 1 * 32 + l31) * LPITCH + kc];
      acc0 = __builtin_amdgcn_mfma_f32_32x32x16_bf16(a0, bfr, acc0, 0, 0, 0);
      acc1 = __builtin_amdgcn_mfma_f32_32x32x16_bf16(a1, bfr, acc1, 0, 0, 0);
    }
  }

  const int p = p0 + nt * 32 + l31;
  const bool pok = (p < POI_);
  const float bp = pok ? bpart[p] : 0.f;
#pragma unroll
  for (int m = 0; m < 2; ++m) {
    const f32x16& a = m ? acc1 : acc0;
#pragma unroll
    for (int r = 0; r < 16; ++r) {
      const int brow = b0 + mh * 64 + m * 32 + (r & 3) + 8 * (r >> 2) + 4 * lhi;
      if (pok) out[(size_t)brow * POI_ + p] = a[r] + bp;
    }
  }
}

// ---------------------------------------------------------------------------
extern "C" void kernel_launch(void* const* d_in, const int* in_sizes, int n_in,
                              void* d_out, int out_size, void* d_ws, size_t ws_size,
                              hipStream_t stream) {
  const float* u     = (const float*)d_in[0];
  const float* lmap  = (const float*)d_in[1];
  const float* rw    = (const float*)d_in[2];
  const float* wdim  = (const float*)d_in[3];
  const float* bdim  = (const float*)d_in[4];
  const float* wpart = (const float*)d_in[5];
  const float* bpart = (const float*)d_in[6];
  float* out = (float*)d_out;

  // ---- workspace layout (bytes; ~50 MB total) ----
  char* W = (char*)d_ws;
  float* bl        = (float*)W;      W += 802816;     // [1000][200] f32
  _Float16* c1     = (_Float16*)W;   W += 458752;     // [1024][224]
  _Float16* c2     = (_Float16*)W;   W += 458752;
  _Float16* un1    = (_Float16*)W;   W += 6815744;    // [256][208][64]
  _Float16* un2    = (_Float16*)W;   W += 6815744;
  _Float16* ut1    = (_Float16*)W;   W += 7340032;    // [256][64][224]
  _Float16* ut2    = (_Float16*)W;   W += 7340032;
  unsigned short* h_bf16 = (unsigned short*)W; W += 524288;   // [256][1024]
  float* part      = (float*)W;      W += 6400000;    // [8][1000][200] f32
  float* umap      = (float*)W;      W += 13107200;   // [256][200][64] f32

  hipMemcpyAsync(bl, rw, (size_t)HCN_ * L_ * sizeof(float),
                 hipMemcpyDeviceToDevice, stream);
  hipMemsetAsync(part, 0, 6400000, stream);
  k_umap<<<800, 256, 0, stream>>>(u, lmap, umap);
  k_prep2<<<256, 256, 0, stream>>>(umap, un1, un2, ut1, ut2);

  // t = 0: no partials yet
  k_softmax2<0><<<256, 256, 0, stream>>>(bl, part, c1, c2);
  k_iter<1, 0><<<1024, 256, 0, stream>>>(c1, c2, un1, un2, ut1, ut2,
                                         wdim, bdim, part, h_bf16);
  // t = 1: fold in t=0 partials (and zero slabs)
  k_softmax2<1><<<256, 256, 0, stream>>>(bl, part, c1, c2);
  k_iter<1, 0><<<1024, 256, 0, stream>>>(c1, c2, un1, un2, ut1, ut2,
                                         wdim, bdim, part, h_bf16);
  // t = 2: fold in t=1 partials; emit h, no UV
  k_softmax2<1><<<256, 256, 0, stream>>>(bl, part, c1, c2);
  k_iter<0, 1><<<1024, 256, 0, stream>>>(c1, c2, un1, un2, ut1, ut2,
                                         wdim, bdim, part, h_bf16);

  k_out_mfma<<<dim3(157, 2), 512, 0, stream>>>(h_bf16, wpart, bpart, out);
}

// Round 11
// 460.785 us; speedup vs baseline: 1.2786x; 1.2786x over previous
//
#include <hip/hip_runtime.h>

#define B_    256
#define L_    200
#define EMB_  128
#define HD_   64
#define HCN_  1000
#define POI_  20000
#define EPS_  1e-8f
#define CP    224          // padded L for c / ut k-dim (7 chunks of 32)
#define UNR   208          // umap-native rows (l), rows 200..207 zero
#define NSLAB 64           // per-bg partial slabs (plain stores, disjoint)
#define SROW  1024         // slab row count (padded)
#define SPL   208          // slab l pitch (padded)

// power-of-2 pre-scales keep fp16 second-splits in the normal range
#define CSC   16384.0f     // c scale (2^14)
#define USC   256.0f       // umap scale (2^8)
#define VSC   1024.0f      // v scale (2^10)
#define SV_DESC (1.0f / (CSC * USC))   // 2^-22, exact
#define UV_DESC (1.0f / (VSC * USC))   // 2^-18, exact

typedef _Float16 half8 __attribute__((ext_vector_type(8)));
typedef __bf16  bf16x8 __attribute__((ext_vector_type(8)));
typedef float   f32x4  __attribute__((ext_vector_type(4)));
typedef float   f32x16 __attribute__((ext_vector_type(16)));

__device__ __forceinline__ unsigned short f2bf(float f) {
  union { float f; unsigned int u; } v; v.f = f;
  unsigned int r = (v.u + 0x7FFFu + ((v.u >> 16) & 1u)) >> 16;  // RNE
  return (unsigned short)r;
}
// 2-way fp16 split of a PRE-SCALED value: x ~= s1+s2 to ~2^-22 relative
__device__ __forceinline__ void split2h(float x, _Float16& s1, _Float16& s2) {
  s1 = (_Float16)x;
  s2 = (_Float16)(x - (float)s1);
}

// 3-pass split product: drops s2*t2 (~2^-22 rel, same order as split residual)
#define THREEPASS(acc, A1f, A2f, B1f, B2f)                                 \
  acc = __builtin_amdgcn_mfma_f32_16x16x32_f16(A2f, B1f, acc, 0, 0, 0);    \
  acc = __builtin_amdgcn_mfma_f32_16x16x32_f16(A1f, B2f, acc, 0, 0, 0);    \
  acc = __builtin_amdgcn_mfma_f32_16x16x32_f16(A1f, B1f, acc, 0, 0, 0);

// ---------------------------------------------------------------------------
// k_umap: u_map[b,l,:] = u[b,l,:] @ l_map_h  (fp32 — routing precision source)
__global__ __launch_bounds__(256) void k_umap(const float* __restrict__ u,
                                              const float* __restrict__ lmap,
                                              float* __restrict__ umap) {
  __shared__ __align__(16) float lm[EMB_ * HD_];   // 32 KB
  for (int i = threadIdx.x; i < EMB_ * HD_; i += 256) lm[i] = lmap[i];
  __syncthreads();
  const int wave = threadIdx.x >> 6, lane = threadIdx.x & 63;
  const int wid = blockIdx.x * 4 + wave;
  for (int row = wid; row < B_ * L_; row += 3200) {
    const float* ur = u + (size_t)row * EMB_;
    float a0 = ur[lane];
    float a1 = ur[lane + 64];
    float acc = 0.f;
#pragma unroll
    for (int k = 0; k < 64; ++k)
      acc = fmaf(__shfl(a0, k), lm[k * HD_ + lane], acc);
#pragma unroll
    for (int k = 0; k < 64; ++k)
      acc = fmaf(__shfl(a1, k), lm[(k + 64) * HD_ + lane], acc);
    umap[(size_t)row * HD_ + lane] = acc;
  }
}

// ---------------------------------------------------------------------------
// k_prep2: umap[b] fp32 -> fp16 2-splits of (umap*USC), native [b][208][64]
// (rows 200..207 zero) and transposed [b][64][224] (cols 200..223 zero).
__global__ __launch_bounds__(256) void k_prep2(const float* __restrict__ umap,
    _Float16* __restrict__ un1, _Float16* __restrict__ un2,
    _Float16* __restrict__ ut1, _Float16* __restrict__ ut2) {
  __shared__ __align__(16) float us[CP][68];   // 60.9 KB
  const int b = blockIdx.x;
  const float* ub = umap + (size_t)b * L_ * HD_;
  for (int i = threadIdx.x; i < CP * HD_; i += 256) {
    int l = i >> 6, d = i & 63;
    us[l][d] = (l < L_) ? ub[l * HD_ + d] * USC : 0.f;
  }
  __syncthreads();
  // native: (row 208, oct 8)
  for (int s = threadIdx.x; s < UNR * 8; s += 256) {
    int row = s >> 3, oct = s & 7;
    _Float16 t1[8], t2[8];
#pragma unroll
    for (int j = 0; j < 8; ++j) split2h(us[row][oct * 8 + j], t1[j], t2[j]);
    size_t dst = ((size_t)b * UNR + row) * HD_ + oct * 8;
    *(uint4*)&un1[dst] = *(uint4*)t1;
    *(uint4*)&un2[dst] = *(uint4*)t2;
  }
  // transposed: (d 64, l-oct 28)
  for (int s = threadIdx.x; s < HD_ * 28; s += 256) {
    int d = s / 28, lo8 = s % 28;
    _Float16 t1[8], t2[8];
#pragma unroll
    for (int j = 0; j < 8; ++j) split2h(us[lo8 * 8 + j][d], t1[j], t2[j]);
    size_t dst = ((size_t)b * HD_ + d) * CP + lo8 * 8;
    *(uint4*)&ut1[dst] = *(uint4*)t1;
    *(uint4*)&ut2[dst] = *(uint4*)t2;
  }
}

// ---------------------------------------------------------------------------
// k_softmax2: (SUM) fold 64 plain-store slabs into b[row,:] (write back; no
// zeroing needed — every slab slot is rewritten each k_iter); then
// c[row,:] = softmax(b[row,:]) -> fp16 2-splits of (c*CSC), [1024][224];
// rows 1000..1023 and cols 200..223 exact zero.
template<int SUM>
__global__ __launch_bounds__(256) void k_softmax2(float* __restrict__ bl,
    const float* __restrict__ part,
    _Float16* __restrict__ c1, _Float16* __restrict__ c2) {
  const int wave = threadIdx.x >> 6, lane = threadIdx.x & 63;
  const int row = blockIdx.x * 4 + wave;                 // 0..1023
  const size_t rb = (size_t)row * CP;
  if (row >= HCN_) {
    c1[rb + lane] = (_Float16)0.f;       c2[rb + lane] = (_Float16)0.f;
    c1[rb + lane + 64] = (_Float16)0.f;  c2[rb + lane + 64] = (_Float16)0.f;
    c1[rb + lane + 128] = (_Float16)0.f; c2[rb + lane + 128] = (_Float16)0.f;
    if (lane < 32) { c1[rb + 192 + lane] = (_Float16)0.f; c2[rb + 192 + lane] = (_Float16)0.f; }
    return;
  }
  float* br = bl + (size_t)row * L_;
  float x0 = br[lane];
  float x1 = br[lane + 64];
  float x2 = br[lane + 128];
  float x3 = (lane < 8) ? br[lane + 192] : -3.0e38f;
  if (SUM) {
#pragma unroll 8
    for (int s = 0; s < NSLAB; ++s) {
      const float* p = part + ((size_t)s * SROW + row) * SPL;
      x0 += p[lane];
      x1 += p[lane + 64];
      x2 += p[lane + 128];
      if (lane < 8) x3 += p[lane + 192];
    }
    br[lane] = x0; br[lane + 64] = x1; br[lane + 128] = x2;
    if (lane < 8) br[lane + 192] = x3;
  }
  float m = fmaxf(fmaxf(x0, x1), fmaxf(x2, x3));
#pragma unroll
  for (int off = 32; off; off >>= 1) m = fmaxf(m, __shfl_xor(m, off));
  float e0 = expf(x0 - m), e1 = expf(x1 - m), e2 = expf(x2 - m);
  float e3 = (lane < 8) ? expf(x3 - m) : 0.f;
  float ssum = e0 + e1 + e2 + e3;
#pragma unroll
  for (int off = 32; off; off >>= 1) ssum += __shfl_xor(ssum, off);
  float inv = CSC / ssum;
  _Float16 s1, s2;
  split2h(e0 * inv, s1, s2); c1[rb + lane] = s1;       c2[rb + lane] = s2;
  split2h(e1 * inv, s1, s2); c1[rb + lane + 64] = s1;  c2[rb + lane + 64] = s2;
  split2h(e2 * inv, s1, s2); c1[rb + lane + 128] = s1; c2[rb + lane + 128] = s2;
  if (lane < 8) {
    split2h(e3 * inv, s1, s2); c1[rb + 192 + lane] = s1; c2[rb + 192 + lane] = s2;
  } else if (lane < 32) {
    c1[rb + 192 + lane] = (_Float16)0.f; c2[rb + 192 + lane] = (_Float16)0.f;
  }
}

// ---------------------------------------------------------------------------
// k_iter: fused routing iteration, fp16 2-split / 3-pass, pre-scaled.
// Per block: 4 batches x 64 h-rows. LDS-staged operands (round-9 structure).
// Grid 1024, decode xcd=id&7, ht=(id>>3)&15, bgH=id>>7, bg=xcd+8*bgH:
// all 16 ht-blocks of one bg share id%8 (one XCD) -> operand L2 locality.
// UV partials: plain stores into slab part[bg] (disjoint (bg,ht) regions,
// full coverage every launch -> no atomics, no zeroing).
// HOUT writes h directly as padded bf16 [256][1024].
template<int UV, int HOUT>
__global__ __launch_bounds__(256, 3) void k_iter(
    const _Float16* __restrict__ c1p, const _Float16* __restrict__ c2p,
    const _Float16* __restrict__ un1, const _Float16* __restrict__ un2,
    const _Float16* __restrict__ ut1, const _Float16* __restrict__ ut2,
    const float* __restrict__ wdim, const float* __restrict__ bdim,
    float* __restrict__ part, unsigned short* __restrict__ hb) {
  // union region: ut_s [2][2][64][40] (20,480 B) / un_s [2][208][40] (33,280 B)
  __shared__ __align__(16) _Float16 smem[16640];
  __shared__ __align__(16) _Float16 v_s[2][64][72];   // 18,432 B (split-indexed)
  typedef _Float16 (*UTarr)[2][64][40];
  typedef _Float16 (*UNarr)[208][40];
  UTarr UT = reinterpret_cast<UTarr>(smem);
  UNarr UN = reinterpret_cast<UNarr>(smem);

  const int id = blockIdx.x;
  const int xcd = id & 7;
  const int ht  = (id >> 3) & 15;
  const int bgH = id >> 7;                      // 0..7
  const int bg  = xcd + (bgH << 3);             // 0..63; bg%8 == id%8 (XCD pin)
  const int h0 = ht * 64;
  const int b0 = bg * 4;
  const int tid = threadIdx.x;
  const int wave = tid >> 6, lane = tid & 63;
  const int l15 = lane & 15, oc = lane >> 4;
  const int rowA = h0 + wave * 16 + l15;     // A-frag row (c row / v row)
  const int rowC = h0 + wave * 16 + oc * 4;  // C/D row base (+r)

#define STAGE_UT(cck, bf) {                                                    \
    const int d_ = tid >> 2, q_ = tid & 3;                                     \
    const size_t so_ = ((size_t)b * HD_ + d_) * CP + (cck) * 32 + q_ * 8;      \
    *(uint4*)&UT[bf][0][d_][q_ * 8] = *(const uint4*)&ut1[so_];                \
    *(uint4*)&UT[bf][1][d_][q_ * 8] = *(const uint4*)&ut2[so_];                \
  }

#define STAGE_UN(half_) {                                                      \
    _Pragma("unroll")                                                          \
    for (int j_ = 0; j_ < 4; ++j_) {                                           \
      int t_ = tid + 256 * j_;                                                 \
      if (t_ < 832) {                                                          \
        int row_ = t_ >> 2, q_ = t_ & 3;                                       \
        const size_t so_ = ((size_t)b * UNR + row_) * HD_ + (half_) * 32 + q_ * 8; \
        *(uint4*)&UN[0][row_][q_ * 8] = *(const uint4*)&un1[so_];              \
        *(uint4*)&UN[1][row_][q_ * 8] = *(const uint4*)&un2[so_];              \
      } } }

  // hoisted A fragments (c rows; invariant over the batches)
  half8 a_f[7][2];
#pragma unroll
  for (int ck = 0; ck < 7; ++ck) {
    const size_t off = (size_t)rowA * CP + ck * 32 + oc * 8;
    a_f[ck][0] = *(const half8*)&c1p[off];
    a_f[ck][1] = *(const half8*)&c2p[off];
  }

  f32x4 acc_uv[13];
  if (UV) {
#pragma unroll
    for (int nt = 0; nt < 13; ++nt) acc_uv[nt] = (f32x4){0.f, 0.f, 0.f, 0.f};
  }
  float wd[4] = {0.f, 0.f, 0.f, 0.f};
  float bd = 0.f;
  if (HOUT) {
#pragma unroll
    for (int nt = 0; nt < 4; ++nt) wd[nt] = wdim[nt * 16 + l15];
    bd = bdim[0];
  }

  for (int bi = 0; bi < 4; ++bi) {
    const int b = b0 + bi;
    // ---------------- SV: s = c @ umap[b] (scaled 2^22) ----------------
    f32x4 acc_s[4];
#pragma unroll
    for (int nt = 0; nt < 4; ++nt) acc_s[nt] = (f32x4){0.f, 0.f, 0.f, 0.f};
    STAGE_UT(0, 0);
    __syncthreads();
#pragma unroll
    for (int ck = 0; ck < 7; ++ck) {
      if (ck < 6) STAGE_UT(ck + 1, (ck + 1) & 1);
      const int cb = ck & 1;
#pragma unroll
      for (int nt = 0; nt < 4; ++nt) {
        const half8 b1 = *(const half8*)&UT[cb][0][nt * 16 + l15][oc * 8];
        const half8 b2 = *(const half8*)&UT[cb][1][nt * 16 + l15][oc * 8];
        THREEPASS(acc_s[nt], a_f[ck][0], a_f[ck][1], b1, b2);
      }
      __syncthreads();
    }
    // ---------------- squash (in-register, descaled) ----------------
    float xdesc[4][4];   // [nt][r]
#pragma unroll
    for (int nt = 0; nt < 4; ++nt)
#pragma unroll
      for (int r = 0; r < 4; ++r) xdesc[nt][r] = acc_s[nt][r] * SV_DESC;
    float gg[4], hq[4];
#pragma unroll
    for (int r = 0; r < 4; ++r) {
      float sq = 0.f, hpp = 0.f;
#pragma unroll
      for (int nt = 0; nt < 4; ++nt) {
        float x = xdesc[nt][r];
        sq += x * x;
        if (HOUT) hpp += x * wd[nt];
      }
#pragma unroll
      for (int off = 8; off; off >>= 1) {
        sq += __shfl_xor(sq, off);
        if (HOUT) hpp += __shfl_xor(hpp, off);
      }
      gg[r] = sq / ((1.f + sq) * sqrtf(sq + EPS_));
      if (HOUT) hq[r] = gg[r] * hpp + bd;
    }
    if (HOUT && l15 == 0) {
      // padded bf16 h write: rows >= 1000 exact zero (rowC is 4-aligned)
      ushort4 hv4;
      if (rowC < HCN_) {
        hv4.x = f2bf(hq[0]); hv4.y = f2bf(hq[1]);
        hv4.z = f2bf(hq[2]); hv4.w = f2bf(hq[3]);
      } else {
        hv4.x = hv4.y = hv4.z = hv4.w = 0;
      }
      *(ushort4*)&hb[(size_t)b * 1024 + rowC] = hv4;
    }
    // ---------------- UV: acc_uv += v @ umap[b]^T ----------------
    if (UV) {
#pragma unroll
      for (int nt = 0; nt < 4; ++nt)
#pragma unroll
        for (int r = 0; r < 4; ++r) {
          _Float16 s1, s2;
          split2h(VSC * gg[r] * xdesc[nt][r], s1, s2);
          const int vr = wave * 16 + oc * 4 + r, vc = nt * 16 + l15;
          v_s[0][vr][vc] = s1; v_s[1][vr][vc] = s2;
        }
      __syncthreads();
#pragma unroll
      for (int half = 0; half < 2; ++half) {
        STAGE_UN(half);
        __syncthreads();
        const int vo = half * 32 + oc * 8;
        const half8 av1 = *(const half8*)&v_s[0][wave * 16 + l15][vo];
        const half8 av2 = *(const half8*)&v_s[1][wave * 16 + l15][vo];
#pragma unroll
        for (int nt = 0; nt < 13; ++nt) {
          const half8 b1 = *(const half8*)&UN[0][nt * 16 + l15][oc * 8];
          const half8 b2 = *(const half8*)&UN[1][nt * 16 + l15][oc * 8];
          THREEPASS(acc_uv[nt], av1, av2, b1, b2);
        }
        __syncthreads();
      }
    }
  }
  if (UV) {
    // plain stores into this bg's slab (regions disjoint by (bg,ht); rows
    // 0..1023 and l 0..207 all in-range in the padded slab — no guards)
    float* pp = part + (size_t)bg * SROW * SPL;
#pragma unroll
    for (int nt = 0; nt < 13; ++nt)
#pragma unroll
      for (int r = 0; r < 4; ++r)
        pp[(size_t)(rowC + r) * SPL + nt * 16 + l15] = acc_uv[nt][r] * UV_DESC;
  }
#undef STAGE_UT
#undef STAGE_UN
}

// ---------------------------------------------------------------------------
// k_out_mfma: out[b,p] = sum_h h[b,h]*w_part[p,h] + b_part[p]  via bf16 MFMA.
#define KPAD 1024
#define LPITCH 72
__global__ __launch_bounds__(512) void k_out_mfma(const unsigned short* __restrict__ hb,
                                                  const float* __restrict__ wpart,
                                                  const float* __restrict__ bpart,
                                                  float* __restrict__ out) {
  __shared__ __align__(16) unsigned short w_lds[128 * LPITCH];  // 18432 B
  __shared__ __align__(16) unsigned short h_lds[128 * LPITCH];  // 18432 B
  const int p0 = blockIdx.x * 128;
  const int b0 = blockIdx.y * 128;
  const int t = threadIdx.x;
  const int wave = t >> 6, lane = t & 63;
  const int nt = wave & 3, mh = wave >> 2;
  const int l31 = lane & 31, lhi = lane >> 5;

  f32x16 acc0 = {};
  f32x16 acc1 = {};

  const int wrow = t >> 2;
  const int wq0  = (t & 3) * 4;
  int prow = p0 + wrow; if (prow > POI_ - 1) prow = POI_ - 1;
  const float* wrp = wpart + (size_t)prow * HCN_;

  for (int ch = 0; ch < 16; ++ch) {
    const int k0 = ch * 64;
    __syncthreads();
#pragma unroll
    for (int qq = 0; qq < 4; ++qq) {
      const int q = wq0 + qq;
      float4 wv;
      if (k0 + q * 4 + 3 < HCN_) {
        wv = *(const float4*)(wrp + k0 + q * 4);
      } else {
        float x0 = (k0 + q * 4 + 0 < HCN_) ? wrp[k0 + q * 4 + 0] : 0.f;
        float x1 = (k0 + q * 4 + 1 < HCN_) ? wrp[k0 + q * 4 + 1] : 0.f;
        float x2 = (k0 + q * 4 + 2 < HCN_) ? wrp[k0 + q * 4 + 2] : 0.f;
        float x3 = (k0 + q * 4 + 3 < HCN_) ? wrp[k0 + q * 4 + 3] : 0.f;
        wv = make_float4(x0, x1, x2, x3);
      }
      ushort4 bv;
      bv.x = f2bf(wv.x); bv.y = f2bf(wv.y); bv.z = f2bf(wv.z); bv.w = f2bf(wv.w);
      *(ushort4*)&w_lds[wrow * LPITCH + q * 4] = bv;
    }
#pragma unroll
    for (int n = 0; n < 2; ++n) {
      const int u = t + n * 512;
      const int hrow = u >> 3, hc = u & 7;
      const uint4 hv = *(const uint4*)(hb + (size_t)(b0 + hrow) * KPAD + k0 + hc * 8);
      *(uint4*)&h_lds[hrow * LPITCH + hc * 8] = hv;
    }
    __syncthreads();
#pragma unroll
    for (int ks = 0; ks < 4; ++ks) {
      const int kc = ks * 16 + lhi * 8;
      bf16x8 bfr = *(const bf16x8*)&w_lds[(nt * 32 + l31) * LPITCH + kc];
      bf16x8 a0  = *(const bf16x8*)&h_lds[(mh * 64 + 0 * 32 + l31) * LPITCH + kc];
      bf16x8 a1  = *(const bf16x8*)&h_lds[(mh * 64 + 1 * 32 + l31) * LPITCH + kc];
      acc0 = __builtin_amdgcn_mfma_f32_32x32x16_bf16(a0, bfr, acc0, 0, 0, 0);
      acc1 = __builtin_amdgcn_mfma_f32_32x32x16_bf16(a1, bfr, acc1, 0, 0, 0);
    }
  }

  const int p = p0 + nt * 32 + l31;
  const bool pok = (p < POI_);
  const float bp = pok ? bpart[p] : 0.f;
#pragma unroll
  for (int m = 0; m < 2; ++m) {
    const f32x16& a = m ? acc1 : acc0;
#pragma unroll
    for (int r = 0; r < 16; ++r) {
      const int brow = b0 + mh * 64 + m * 32 + (r & 3) + 8 * (r >> 2) + 4 * lhi;
      if (pok) out[(size_t)brow * POI_ + p] = a[r] + bp;
    }
  }
}

// ---------------------------------------------------------------------------
extern "C" void kernel_launch(void* const* d_in, const int* in_sizes, int n_in,
                              void* d_out, int out_size, void* d_ws, size_t ws_size,
                              hipStream_t stream) {
  const float* u     = (const float*)d_in[0];
  const float* lmap  = (const float*)d_in[1];
  const float* rw    = (const float*)d_in[2];
  const float* wdim  = (const float*)d_in[3];
  const float* bdim  = (const float*)d_in[4];
  const float* wpart = (const float*)d_in[5];
  const float* bpart = (const float*)d_in[6];
  float* out = (float*)d_out;

  // ---- workspace layout (bytes; ~85 MB total) ----
  char* W = (char*)d_ws;
  float* bl        = (float*)W;      W += 802816;     // [1000][200] f32
  _Float16* c1     = (_Float16*)W;   W += 458752;     // [1024][224]
  _Float16* c2     = (_Float16*)W;   W += 458752;
  _Float16* un1    = (_Float16*)W;   W += 6815744;    // [256][208][64]
  _Float16* un2    = (_Float16*)W;   W += 6815744;
  _Float16* ut1    = (_Float16*)W;   W += 7340032;    // [256][64][224]
  _Float16* ut2    = (_Float16*)W;   W += 7340032;
  unsigned short* h_bf16 = (unsigned short*)W; W += 524288;   // [256][1024]
  float* part      = (float*)W;      W += (size_t)NSLAB * SROW * SPL * 4;  // 54.5 MB
  // umap f32 (13.1 MB) overlaps part: dead after k_prep2, part written later.
  float* umap      = part;

  hipMemcpyAsync(bl, rw, (size_t)HCN_ * L_ * sizeof(float),
                 hipMemcpyDeviceToDevice, stream);
  k_umap<<<800, 256, 0, stream>>>(u, lmap, umap);
  k_prep2<<<256, 256, 0, stream>>>(umap, un1, un2, ut1, ut2);

  // t = 0: no partials yet
  k_softmax2<0><<<256, 256, 0, stream>>>(bl, part, c1, c2);
  k_iter<1, 0><<<1024, 256, 0, stream>>>(c1, c2, un1, un2, ut1, ut2,
                                         wdim, bdim, part, h_bf16);
  // t = 1: fold in t=0 partials
  k_softmax2<1><<<256, 256, 0, stream>>>(bl, part, c1, c2);
  k_iter<1, 0><<<1024, 256, 0, stream>>>(c1, c2, un1, un2, ut1, ut2,
                                         wdim, bdim, part, h_bf16);
  // t = 2: fold in t=1 partials; emit h, no UV
  k_softmax2<1><<<256, 256, 0, stream>>>(bl, part, c1, c2);
  k_iter<0, 1><<<1024, 256, 0, stream>>>(c1, c2, un1, un2, ut1, ut2,
                                         wdim, bdim, part, h_bf16);

  k_out_mfma<<<dim3(157, 2), 512, 0, stream>>>(h_bf16, wpart, bpart, out);
}

// Round 12
// 438.597 us; speedup vs baseline: 1.3433x; 1.0506x over previous
//
#include <hip/hip_runtime.h>

#define B_    256
#define L_    200
#define EMB_  128
#define HD_   64
#define HCN_  1000
#define POI_  20000
#define EPS_  1e-8f
#define CP    224          // padded L for c / ut k-dim (7 chunks of 32)
#define UNR   208          // umap-native rows (l), rows 200..207 zero
#define NSLAB 64           // per-bg partial slabs (plain stores, disjoint)
#define SROW  1024         // slab row count (padded)
#define SPL   208          // slab l pitch (padded)

// power-of-2 pre-scales keep fp16 second-splits in the normal range
#define CSC   16384.0f     // c scale (2^14)
#define USC   256.0f       // umap scale (2^8)
#define VSC   1024.0f      // v scale (2^10)
#define SV_DESC (1.0f / (CSC * USC))   // 2^-22, exact
#define UV_DESC (1.0f / (VSC * USC))   // 2^-18, exact

typedef _Float16 half8 __attribute__((ext_vector_type(8)));
typedef __bf16  bf16x8 __attribute__((ext_vector_type(8)));
typedef float   f32x4  __attribute__((ext_vector_type(4)));
typedef float   f32x16 __attribute__((ext_vector_type(16)));

__device__ __forceinline__ unsigned short f2bf(float f) {
  union { float f; unsigned int u; } v; v.f = f;
  unsigned int r = (v.u + 0x7FFFu + ((v.u >> 16) & 1u)) >> 16;  // RNE
  return (unsigned short)r;
}
// 2-way fp16 split of a PRE-SCALED value: x ~= s1+s2 to ~2^-22 relative
__device__ __forceinline__ void split2h(float x, _Float16& s1, _Float16& s2) {
  s1 = (_Float16)x;
  s2 = (_Float16)(x - (float)s1);
}

// 3-pass split product: drops s2*t2 (~2^-22 rel, same order as split residual)
#define THREEPASS(acc, A1f, A2f, B1f, B2f)                                 \
  acc = __builtin_amdgcn_mfma_f32_16x16x32_f16(A2f, B1f, acc, 0, 0, 0);    \
  acc = __builtin_amdgcn_mfma_f32_16x16x32_f16(A1f, B2f, acc, 0, 0, 0);    \
  acc = __builtin_amdgcn_mfma_f32_16x16x32_f16(A1f, B1f, acc, 0, 0, 0);

// ---------------------------------------------------------------------------
// k_umap: u_map[b,l,:] = u[b,l,:] @ l_map_h  (fp32 — routing precision source)
__global__ __launch_bounds__(256) void k_umap(const float* __restrict__ u,
                                              const float* __restrict__ lmap,
                                              float* __restrict__ umap) {
  __shared__ __align__(16) float lm[EMB_ * HD_];   // 32 KB
  for (int i = threadIdx.x; i < EMB_ * HD_; i += 256) lm[i] = lmap[i];
  __syncthreads();
  const int wave = threadIdx.x >> 6, lane = threadIdx.x & 63;
  const int wid = blockIdx.x * 4 + wave;
  for (int row = wid; row < B_ * L_; row += 3200) {
    const float* ur = u + (size_t)row * EMB_;
    float a0 = ur[lane];
    float a1 = ur[lane + 64];
    float acc = 0.f;
#pragma unroll
    for (int k = 0; k < 64; ++k)
      acc = fmaf(__shfl(a0, k), lm[k * HD_ + lane], acc);
#pragma unroll
    for (int k = 0; k < 64; ++k)
      acc = fmaf(__shfl(a1, k), lm[(k + 64) * HD_ + lane], acc);
    umap[(size_t)row * HD_ + lane] = acc;
  }
}

// ---------------------------------------------------------------------------
// k_prep2: umap[b] fp32 -> fp16 2-splits of (umap*USC), native [b][208][64]
// (rows 200..207 zero) and transposed [b][64][224] (cols 200..223 zero).
__global__ __launch_bounds__(256) void k_prep2(const float* __restrict__ umap,
    _Float16* __restrict__ un1, _Float16* __restrict__ un2,
    _Float16* __restrict__ ut1, _Float16* __restrict__ ut2) {
  __shared__ __align__(16) float us[CP][68];   // 60.9 KB
  const int b = blockIdx.x;
  const float* ub = umap + (size_t)b * L_ * HD_;
  for (int i = threadIdx.x; i < CP * HD_; i += 256) {
    int l = i >> 6, d = i & 63;
    us[l][d] = (l < L_) ? ub[l * HD_ + d] * USC : 0.f;
  }
  __syncthreads();
  // native: (row 208, oct 8)
  for (int s = threadIdx.x; s < UNR * 8; s += 256) {
    int row = s >> 3, oct = s & 7;
    _Float16 t1[8], t2[8];
#pragma unroll
    for (int j = 0; j < 8; ++j) split2h(us[row][oct * 8 + j], t1[j], t2[j]);
    size_t dst = ((size_t)b * UNR + row) * HD_ + oct * 8;
    *(uint4*)&un1[dst] = *(uint4*)t1;
    *(uint4*)&un2[dst] = *(uint4*)t2;
  }
  // transposed: (d 64, l-oct 28)
  for (int s = threadIdx.x; s < HD_ * 28; s += 256) {
    int d = s / 28, lo8 = s % 28;
    _Float16 t1[8], t2[8];
#pragma unroll
    for (int j = 0; j < 8; ++j) split2h(us[lo8 * 8 + j][d], t1[j], t2[j]);
    size_t dst = ((size_t)b * HD_ + d) * CP + lo8 * 8;
    *(uint4*)&ut1[dst] = *(uint4*)t1;
    *(uint4*)&ut2[dst] = *(uint4*)t2;
  }
}

// ---------------------------------------------------------------------------
// k_softmax2: (SUM) fold 64 plain-store slabs into b[row,:] (write back; no
// zeroing needed — every slab slot is rewritten each k_iter); then
// c[row,:] = softmax(b[row,:]) -> fp16 2-splits of (c*CSC), [1024][224];
// rows 1000..1023 and cols 200..223 exact zero.
template<int SUM>
__global__ __launch_bounds__(256) void k_softmax2(float* __restrict__ bl,
    const float* __restrict__ part,
    _Float16* __restrict__ c1, _Float16* __restrict__ c2) {
  const int wave = threadIdx.x >> 6, lane = threadIdx.x & 63;
  const int row = blockIdx.x * 4 + wave;                 // 0..1023
  const size_t rb = (size_t)row * CP;
  if (row >= HCN_) {
    c1[rb + lane] = (_Float16)0.f;       c2[rb + lane] = (_Float16)0.f;
    c1[rb + lane + 64] = (_Float16)0.f;  c2[rb + lane + 64] = (_Float16)0.f;
    c1[rb + lane + 128] = (_Float16)0.f; c2[rb + lane + 128] = (_Float16)0.f;
    if (lane < 32) { c1[rb + 192 + lane] = (_Float16)0.f; c2[rb + 192 + lane] = (_Float16)0.f; }
    return;
  }
  float* br = bl + (size_t)row * L_;
  float x0 = br[lane];
  float x1 = br[lane + 64];
  float x2 = br[lane + 128];
  float x3 = (lane < 8) ? br[lane + 192] : -3.0e38f;
  if (SUM) {
#pragma unroll 8
    for (int s = 0; s < NSLAB; ++s) {
      const float* p = part + ((size_t)s * SROW + row) * SPL;
      x0 += p[lane];
      x1 += p[lane + 64];
      x2 += p[lane + 128];
      if (lane < 8) x3 += p[lane + 192];
    }
    br[lane] = x0; br[lane + 64] = x1; br[lane + 128] = x2;
    if (lane < 8) br[lane + 192] = x3;
  }
  float m = fmaxf(fmaxf(x0, x1), fmaxf(x2, x3));
#pragma unroll
  for (int off = 32; off; off >>= 1) m = fmaxf(m, __shfl_xor(m, off));
  float e0 = expf(x0 - m), e1 = expf(x1 - m), e2 = expf(x2 - m);
  float e3 = (lane < 8) ? expf(x3 - m) : 0.f;
  float ssum = e0 + e1 + e2 + e3;
#pragma unroll
  for (int off = 32; off; off >>= 1) ssum += __shfl_xor(ssum, off);
  float inv = CSC / ssum;
  _Float16 s1, s2;
  split2h(e0 * inv, s1, s2); c1[rb + lane] = s1;       c2[rb + lane] = s2;
  split2h(e1 * inv, s1, s2); c1[rb + lane + 64] = s1;  c2[rb + lane + 64] = s2;
  split2h(e2 * inv, s1, s2); c1[rb + lane + 128] = s1; c2[rb + lane + 128] = s2;
  if (lane < 8) {
    split2h(e3 * inv, s1, s2); c1[rb + 192 + lane] = s1; c2[rb + 192 + lane] = s2;
  } else if (lane < 32) {
    c1[rb + 192 + lane] = (_Float16)0.f; c2[rb + 192 + lane] = (_Float16)0.f;
  }
}

// ---------------------------------------------------------------------------
// k_iter: fused routing iteration, fp16 2-split / 3-pass, pre-scaled.
// Per block: 4 batches x 64 h-rows. LDS shrunk to 38.9 KB (UN staged in
// row-groups 112+96 under the 20.5 KB UT union) -> 4 blocks/CU resident.
// Grid 1024, decode xcd=id&7, ht=(id>>3)&15, bgH=id>>7, bg=xcd+8*bgH.
// UV partials: plain stores into slab part[bg]. HOUT -> padded bf16 h.
template<int UV, int HOUT>
__global__ __launch_bounds__(256, 4) void k_iter(
    const _Float16* __restrict__ c1p, const _Float16* __restrict__ c2p,
    const _Float16* __restrict__ un1, const _Float16* __restrict__ un2,
    const _Float16* __restrict__ ut1, const _Float16* __restrict__ ut2,
    const float* __restrict__ wdim, const float* __restrict__ bdim,
    float* __restrict__ part, unsigned short* __restrict__ hb) {
  // union region 20,480 B: UT [2][2][64][40] / UN row-group [2][112][40]
  __shared__ __align__(16) _Float16 smem[10240];
  // v_s only exists in the UV variant (t=2 gets ~20.5 KB total -> 6+ blocks/CU)
  __shared__ __align__(16) _Float16 v_sm[UV ? (2 * 64 * 72) : 2];
  typedef _Float16 (*UTarr)[2][64][40];
  typedef _Float16 (*UNarr)[112][40];
  typedef _Float16 (*VSarr)[64][72];
  UTarr UT = reinterpret_cast<UTarr>(smem);
  UNarr UN = reinterpret_cast<UNarr>(smem);
  VSarr VS = reinterpret_cast<VSarr>(v_sm);

  const int id = blockIdx.x;
  const int xcd = id & 7;
  const int ht  = (id >> 3) & 15;
  const int bgH = id >> 7;                      // 0..7
  const int bg  = xcd + (bgH << 3);             // 0..63; bg%8 == id%8 (XCD pin)
  const int h0 = ht * 64;
  const int b0 = bg * 4;
  const int tid = threadIdx.x;
  const int wave = tid >> 6, lane = tid & 63;
  const int l15 = lane & 15, oc = lane >> 4;
  const int rowA = h0 + wave * 16 + l15;     // A-frag row (c row / v row)
  const int rowC = h0 + wave * 16 + oc * 4;  // C/D row base (+r)

#define STAGE_UT(cck, bf) {                                                    \
    const int d_ = tid >> 2, q_ = tid & 3;                                     \
    const size_t so_ = ((size_t)b * HD_ + d_) * CP + (cck) * 32 + q_ * 8;      \
    *(uint4*)&UT[bf][0][d_][q_ * 8] = *(const uint4*)&ut1[so_];                \
    *(uint4*)&UT[bf][1][d_][q_ * 8] = *(const uint4*)&ut2[so_];                \
  }

// stage UN row-group g_ (g0: rows 0..111, g1: rows 112..207) of k-half half_
#define STAGE_UN2(half_, g_, nrows_) {                                        \
    _Pragma("unroll")                                                          \
    for (int j_ = 0; j_ < 2; ++j_) {                                           \
      int t_ = tid + 256 * j_;                                                 \
      if (t_ < (nrows_) * 4) {                                                 \
        int row_ = t_ >> 2, q_ = t_ & 3;                                       \
        const size_t so_ = ((size_t)b * UNR + (g_) * 112 + row_) * HD_         \
                           + (half_) * 32 + q_ * 8;                            \
        *(uint4*)&UN[0][row_][q_ * 8] = *(const uint4*)&un1[so_];              \
        *(uint4*)&UN[1][row_][q_ * 8] = *(const uint4*)&un2[so_];              \
      } } }

  // hoisted A fragments (c rows; invariant over the batches)
  half8 a_f[7][2];
#pragma unroll
  for (int ck = 0; ck < 7; ++ck) {
    const size_t off = (size_t)rowA * CP + ck * 32 + oc * 8;
    a_f[ck][0] = *(const half8*)&c1p[off];
    a_f[ck][1] = *(const half8*)&c2p[off];
  }

  f32x4 acc_uv[13];
  if (UV) {
#pragma unroll
    for (int nt = 0; nt < 13; ++nt) acc_uv[nt] = (f32x4){0.f, 0.f, 0.f, 0.f};
  }
  float wd[4] = {0.f, 0.f, 0.f, 0.f};
  float bd = 0.f;
  if (HOUT) {
#pragma unroll
    for (int nt = 0; nt < 4; ++nt) wd[nt] = wdim[nt * 16 + l15];
    bd = bdim[0];
  }

  for (int bi = 0; bi < 4; ++bi) {
    const int b = b0 + bi;
    // ---------------- SV: s = c @ umap[b] (scaled 2^22) ----------------
    f32x4 acc_s[4];
#pragma unroll
    for (int nt = 0; nt < 4; ++nt) acc_s[nt] = (f32x4){0.f, 0.f, 0.f, 0.f};
    STAGE_UT(0, 0);
    __syncthreads();
#pragma unroll
    for (int ck = 0; ck < 7; ++ck) {
      if (ck < 6) STAGE_UT(ck + 1, (ck + 1) & 1);
      const int cb = ck & 1;
#pragma unroll
      for (int nt = 0; nt < 4; ++nt) {
        const half8 b1 = *(const half8*)&UT[cb][0][nt * 16 + l15][oc * 8];
        const half8 b2 = *(const half8*)&UT[cb][1][nt * 16 + l15][oc * 8];
        THREEPASS(acc_s[nt], a_f[ck][0], a_f[ck][1], b1, b2);
      }
      __syncthreads();
    }
    // ---------------- squash (in-register, descaled) ----------------
    float xdesc[4][4];   // [nt][r]
#pragma unroll
    for (int nt = 0; nt < 4; ++nt)
#pragma unroll
      for (int r = 0; r < 4; ++r) xdesc[nt][r] = acc_s[nt][r] * SV_DESC;
    float gg[4], hq[4];
#pragma unroll
    for (int r = 0; r < 4; ++r) {
      float sq = 0.f, hpp = 0.f;
#pragma unroll
      for (int nt = 0; nt < 4; ++nt) {
        float x = xdesc[nt][r];
        sq += x * x;
        if (HOUT) hpp += x * wd[nt];
      }
#pragma unroll
      for (int off = 8; off; off >>= 1) {
        sq += __shfl_xor(sq, off);
        if (HOUT) hpp += __shfl_xor(hpp, off);
      }
      gg[r] = sq / ((1.f + sq) * sqrtf(sq + EPS_));
      if (HOUT) hq[r] = gg[r] * hpp + bd;
    }
    if (HOUT && l15 == 0) {
      // padded bf16 h write: rows >= 1000 exact zero (rowC is 4-aligned)
      ushort4 hv4;
      if (rowC < HCN_) {
        hv4.x = f2bf(hq[0]); hv4.y = f2bf(hq[1]);
        hv4.z = f2bf(hq[2]); hv4.w = f2bf(hq[3]);
      } else {
        hv4.x = hv4.y = hv4.z = hv4.w = 0;
      }
      *(ushort4*)&hb[(size_t)b * 1024 + rowC] = hv4;
    }
    // ---------------- UV: acc_uv += v @ umap[b]^T ----------------
    if (UV) {
#pragma unroll
      for (int nt = 0; nt < 4; ++nt)
#pragma unroll
        for (int r = 0; r < 4; ++r) {
          _Float16 s1, s2;
          split2h(VSC * gg[r] * xdesc[nt][r], s1, s2);
          const int vr = wave * 16 + oc * 4 + r, vc = nt * 16 + l15;
          VS[0][vr][vc] = s1; VS[1][vr][vc] = s2;
        }
      __syncthreads();   // v_s ready; SV's UT reads all done (region reuse ok)
#pragma unroll
      for (int half = 0; half < 2; ++half) {
        const int vo = half * 32 + oc * 8;
        const half8 av1 = *(const half8*)&VS[0][wave * 16 + l15][vo];
        const half8 av2 = *(const half8*)&VS[1][wave * 16 + l15][vo];
#pragma unroll
        for (int g = 0; g < 2; ++g) {
          STAGE_UN2(half, g, (g ? 96 : 112));
          __syncthreads();            // row-group staged
          if (g == 0) {
#pragma unroll
            for (int nt = 0; nt < 7; ++nt) {
              const half8 b1 = *(const half8*)&UN[0][nt * 16 + l15][oc * 8];
              const half8 b2 = *(const half8*)&UN[1][nt * 16 + l15][oc * 8];
              THREEPASS(acc_uv[nt], av1, av2, b1, b2);
            }
          } else {
#pragma unroll
            for (int nt = 7; nt < 13; ++nt) {
              const half8 b1 = *(const half8*)&UN[0][(nt - 7) * 16 + l15][oc * 8];
              const half8 b2 = *(const half8*)&UN[1][(nt - 7) * 16 + l15][oc * 8];
              THREEPASS(acc_uv[nt], av1, av2, b1, b2);
            }
          }
          __syncthreads();            // row-group consumed
        }
      }
    }
  }
  if (UV) {
    // plain stores into this bg's slab (regions disjoint by (bg,ht))
    float* pp = part + (size_t)bg * SROW * SPL;
#pragma unroll
    for (int nt = 0; nt < 13; ++nt)
#pragma unroll
      for (int r = 0; r < 4; ++r)
        pp[(size_t)(rowC + r) * SPL + nt * 16 + l15] = acc_uv[nt][r] * UV_DESC;
  }
#undef STAGE_UT
#undef STAGE_UN2
}

// ---------------------------------------------------------------------------
// k_out_mfma: out[b,p] = sum_h h[b,h]*w_part[p,h] + b_part[p]  via bf16 MFMA.
#define KPAD 1024
#define LPITCH 72
__global__ __launch_bounds__(512) void k_out_mfma(const unsigned short* __restrict__ hb,
                                                  const float* __restrict__ wpart,
                                                  const float* __restrict__ bpart,
                                                  float* __restrict__ out) {
  __shared__ __align__(16) unsigned short w_lds[128 * LPITCH];  // 18432 B
  __shared__ __align__(16) unsigned short h_lds[128 * LPITCH];  // 18432 B
  const int p0 = blockIdx.x * 128;
  const int b0 = blockIdx.y * 128;
  const int t = threadIdx.x;
  const int wave = t >> 6, lane = t & 63;
  const int nt = wave & 3, mh = wave >> 2;
  const int l31 = lane & 31, lhi = lane >> 5;

  f32x16 acc0 = {};
  f32x16 acc1 = {};

  const int wrow = t >> 2;
  const int wq0  = (t & 3) * 4;
  int prow = p0 + wrow; if (prow > POI_ - 1) prow = POI_ - 1;
  const float* wrp = wpart + (size_t)prow * HCN_;

  for (int ch = 0; ch < 16; ++ch) {
    const int k0 = ch * 64;
    __syncthreads();
#pragma unroll
    for (int qq = 0; qq < 4; ++qq) {
      const int q = wq0 + qq;
      float4 wv;
      if (k0 + q * 4 + 3 < HCN_) {
        wv = *(const float4*)(wrp + k0 + q * 4);
      } else {
        float x0 = (k0 + q * 4 + 0 < HCN_) ? wrp[k0 + q * 4 + 0] : 0.f;
        float x1 = (k0 + q * 4 + 1 < HCN_) ? wrp[k0 + q * 4 + 1] : 0.f;
        float x2 = (k0 + q * 4 + 2 < HCN_) ? wrp[k0 + q * 4 + 2] : 0.f;
        float x3 = (k0 + q * 4 + 3 < HCN_) ? wrp[k0 + q * 4 + 3] : 0.f;
        wv = make_float4(x0, x1, x2, x3);
      }
      ushort4 bv;
      bv.x = f2bf(wv.x); bv.y = f2bf(wv.y); bv.z = f2bf(wv.z); bv.w = f2bf(wv.w);
      *(ushort4*)&w_lds[wrow * LPITCH + q * 4] = bv;
    }
#pragma unroll
    for (int n = 0; n < 2; ++n) {
      const int u = t + n * 512;
      const int hrow = u >> 3, hc = u & 7;
      const uint4 hv = *(const uint4*)(hb + (size_t)(b0 + hrow) * KPAD + k0 + hc * 8);
      *(uint4*)&h_lds[hrow * LPITCH + hc * 8] = hv;
    }
    __syncthreads();
#pragma unroll
    for (int ks = 0; ks < 4; ++ks) {
      const int kc = ks * 16 + lhi * 8;
      bf16x8 bfr = *(const bf16x8*)&w_lds[(nt * 32 + l31) * LPITCH + kc];
      bf16x8 a0  = *(const bf16x8*)&h_lds[(mh * 64 + 0 * 32 + l31) * LPITCH + kc];
      bf16x8 a1  = *(const bf16x8*)&h_lds[(mh * 64 + 1 * 32 + l31) * LPITCH + kc];
      acc0 = __builtin_amdgcn_mfma_f32_32x32x16_bf16(a0, bfr, acc0, 0, 0, 0);
      acc1 = __builtin_amdgcn_mfma_f32_32x32x16_bf16(a1, bfr, acc1, 0, 0, 0);
    }
  }

  const int p = p0 + nt * 32 + l31;
  const bool pok = (p < POI_);
  const float bp = pok ? bpart[p] : 0.f;
#pragma unroll
  for (int m = 0; m < 2; ++m) {
    const f32x16& a = m ? acc1 : acc0;
#pragma unroll
    for (int r = 0; r < 16; ++r) {
      const int brow = b0 + mh * 64 + m * 32 + (r & 3) + 8 * (r >> 2) + 4 * lhi;
      if (pok) out[(size_t)brow * POI_ + p] = a[r] + bp;
    }
  }
}

// ---------------------------------------------------------------------------
extern "C" void kernel_launch(void* const* d_in, const int* in_sizes, int n_in,
                              void* d_out, int out_size, void* d_ws, size_t ws_size,
                              hipStream_t stream) {
  const float* u     = (const float*)d_in[0];
  const float* lmap  = (const float*)d_in[1];
  const float* rw    = (const float*)d_in[2];
  const float* wdim  = (const float*)d_in[3];
  const float* bdim  = (const float*)d_in[4];
  const float* wpart = (const float*)d_in[5];
  const float* bpart = (const float*)d_in[6];
  float* out = (float*)d_out;

  // ---- workspace layout (bytes; ~85 MB total) ----
  char* W = (char*)d_ws;
  float* bl        = (float*)W;      W += 802816;     // [1000][200] f32
  _Float16* c1     = (_Float16*)W;   W += 458752;     // [1024][224]
  _Float16* c2     = (_Float16*)W;   W += 458752;
  _Float16* un1    = (_Float16*)W;   W += 6815744;    // [256][208][64]
  _Float16* un2    = (_Float16*)W;   W += 6815744;
  _Float16* ut1    = (_Float16*)W;   W += 7340032;    // [256][64][224]
  _Float16* ut2    = (_Float16*)W;   W += 7340032;
  unsigned short* h_bf16 = (unsigned short*)W; W += 524288;   // [256][1024]
  float* part      = (float*)W;      W += (size_t)NSLAB * SROW * SPL * 4;  // 54.5 MB
  // umap f32 (13.1 MB) overlaps part: dead after k_prep2, part written later.
  float* umap      = part;

  hipMemcpyAsync(bl, rw, (size_t)HCN_ * L_ * sizeof(float),
                 hipMemcpyDeviceToDevice, stream);
  k_umap<<<800, 256, 0, stream>>>(u, lmap, umap);
  k_prep2<<<256, 256, 0, stream>>>(umap, un1, un2, ut1, ut2);

  // t = 0: no partials yet
  k_softmax2<0><<<256, 256, 0, stream>>>(bl, part, c1, c2);
  k_iter<1, 0><<<1024, 256, 0, stream>>>(c1, c2, un1, un2, ut1, ut2,
                                         wdim, bdim, part, h_bf16);
  // t = 1: fold in t=0 partials
  k_softmax2<1><<<256, 256, 0, stream>>>(bl, part, c1, c2);
  k_iter<1, 0><<<1024, 256, 0, stream>>>(c1, c2, un1, un2, ut1, ut2,
                                         wdim, bdim, part, h_bf16);
  // t = 2: fold in t=1 partials; emit h, no UV
  k_softmax2<1><<<256, 256, 0, stream>>>(bl, part, c1, c2);
  k_iter<0, 1><<<1024, 256, 0, stream>>>(c1, c2, un1, un2, ut1, ut2,
                                         wdim, bdim, part, h_bf16);

  k_out_mfma<<<dim3(157, 2), 512, 0, stream>>>(h_bf16, wpart, bpart, out);
}

// Round 13
// 426.176 us; speedup vs baseline: 1.3825x; 1.0291x over previous
//
#include <hip/hip_runtime.h>

#define B_    256
#define L_    200
#define EMB_  128
#define HD_   64
#define HCN_  1000
#define POI_  20000
#define EPS_  1e-8f
#define CP    224          // padded L for c / ut k-dim (7 chunks of 32)
#define UNR   208          // umap-native rows (l), rows 200..207 zero
#define NSLAB 64           // per-bg partial slabs (plain stores, disjoint)
#define SROW  1024         // slab row count (padded)
#define SPL   208          // slab l pitch (padded)

// power-of-2 pre-scales keep fp16 second-splits in the normal range
#define CSC   16384.0f     // c scale (2^14)
#define USC   256.0f       // umap scale (2^8)
#define VSC   1024.0f      // v scale (2^10)
#define SV_DESC (1.0f / (CSC * USC))   // 2^-22, exact
#define UV_DESC (1.0f / (VSC * USC))   // 2^-18, exact

typedef _Float16 half8 __attribute__((ext_vector_type(8)));
typedef __bf16  bf16x8 __attribute__((ext_vector_type(8)));
typedef float   f32x4  __attribute__((ext_vector_type(4)));
typedef float   f32x16 __attribute__((ext_vector_type(16)));

__device__ __forceinline__ unsigned short f2bf(float f) {
  union { float f; unsigned int u; } v; v.f = f;
  unsigned int r = (v.u + 0x7FFFu + ((v.u >> 16) & 1u)) >> 16;  // RNE
  return (unsigned short)r;
}
// 2-way fp16 split of a PRE-SCALED value: x ~= s1+s2 to ~2^-22 relative
__device__ __forceinline__ void split2h(float x, _Float16& s1, _Float16& s2) {
  s1 = (_Float16)x;
  s2 = (_Float16)(x - (float)s1);
}

// 3-pass split product: drops s2*t2 (~2^-22 rel, same order as split residual)
#define THREEPASS(acc, A1f, A2f, B1f, B2f)                                 \
  acc = __builtin_amdgcn_mfma_f32_16x16x32_f16(A2f, B1f, acc, 0, 0, 0);    \
  acc = __builtin_amdgcn_mfma_f32_16x16x32_f16(A1f, B2f, acc, 0, 0, 0);    \
  acc = __builtin_amdgcn_mfma_f32_16x16x32_f16(A1f, B1f, acc, 0, 0, 0);

// ---------------------------------------------------------------------------
// k_umap: u_map[b,l,:] = u[b,l,:] @ l_map_h  (fp32 — routing precision source)
// ILP-4: four independent k-quarter accumulators break the 128-deep FMA chain
// (round-12 post-mortem: serial chain + 16 rows/wave = 106 us latency-bound).
// Grid 1600 (8 rows/wave); 32 KB LDS -> 4 blocks/CU.
__global__ __launch_bounds__(256) void k_umap(const float* __restrict__ u,
                                              const float* __restrict__ lmap,
                                              float* __restrict__ umap) {
  __shared__ __align__(16) float lm[EMB_ * HD_];   // 32 KB
  for (int i = threadIdx.x; i < EMB_ * HD_; i += 256) lm[i] = lmap[i];
  __syncthreads();
  const int wave = threadIdx.x >> 6, lane = threadIdx.x & 63;
  const int wid = blockIdx.x * 4 + wave;
  for (int row = wid; row < B_ * L_; row += 6400) {
    const float* ur = u + (size_t)row * EMB_;
    float a0 = ur[lane];
    float a1 = ur[lane + 64];
    float acc0 = 0.f, acc1 = 0.f, acc2 = 0.f, acc3 = 0.f;
#pragma unroll
    for (int k = 0; k < 32; ++k) {
      acc0 = fmaf(__shfl(a0, k),      lm[k * HD_ + lane],        acc0);
      acc1 = fmaf(__shfl(a0, k + 32), lm[(k + 32) * HD_ + lane], acc1);
      acc2 = fmaf(__shfl(a1, k),      lm[(k + 64) * HD_ + lane], acc2);
      acc3 = fmaf(__shfl(a1, k + 32), lm[(k + 96) * HD_ + lane], acc3);
    }
    umap[(size_t)row * HD_ + lane] = (acc0 + acc1) + (acc2 + acc3);
  }
}

// ---------------------------------------------------------------------------
// k_prep2: umap[b] fp32 -> fp16 2-splits of (umap*USC), native [b][208][64]
// (rows 200..207 zero) and transposed [b][64][224] (cols 200..223 zero).
__global__ __launch_bounds__(256) void k_prep2(const float* __restrict__ umap,
    _Float16* __restrict__ un1, _Float16* __restrict__ un2,
    _Float16* __restrict__ ut1, _Float16* __restrict__ ut2) {
  __shared__ __align__(16) float us[CP][68];   // 60.9 KB
  const int b = blockIdx.x;
  const float* ub = umap + (size_t)b * L_ * HD_;
  for (int i = threadIdx.x; i < CP * HD_; i += 256) {
    int l = i >> 6, d = i & 63;
    us[l][d] = (l < L_) ? ub[l * HD_ + d] * USC : 0.f;
  }
  __syncthreads();
  // native: (row 208, oct 8)
  for (int s = threadIdx.x; s < UNR * 8; s += 256) {
    int row = s >> 3, oct = s & 7;
    _Float16 t1[8], t2[8];
#pragma unroll
    for (int j = 0; j < 8; ++j) split2h(us[row][oct * 8 + j], t1[j], t2[j]);
    size_t dst = ((size_t)b * UNR + row) * HD_ + oct * 8;
    *(uint4*)&un1[dst] = *(uint4*)t1;
    *(uint4*)&un2[dst] = *(uint4*)t2;
  }
  // transposed: (d 64, l-oct 28)
  for (int s = threadIdx.x; s < HD_ * 28; s += 256) {
    int d = s / 28, lo8 = s % 28;
    _Float16 t1[8], t2[8];
#pragma unroll
    for (int j = 0; j < 8; ++j) split2h(us[lo8 * 8 + j][d], t1[j], t2[j]);
    size_t dst = ((size_t)b * HD_ + d) * CP + lo8 * 8;
    *(uint4*)&ut1[dst] = *(uint4*)t1;
    *(uint4*)&ut2[dst] = *(uint4*)t2;
  }
}

// ---------------------------------------------------------------------------
// k_softmax2: (SUM) fold 64 plain-store slabs into b[row,:] (write back; no
// zeroing needed — every slab slot is rewritten each k_iter); then
// c[row,:] = softmax(b[row,:]) -> fp16 2-splits of (c*CSC), [1024][224];
// rows 1000..1023 and cols 200..223 exact zero.
template<int SUM>
__global__ __launch_bounds__(256) void k_softmax2(float* __restrict__ bl,
    const float* __restrict__ part,
    _Float16* __restrict__ c1, _Float16* __restrict__ c2) {
  const int wave = threadIdx.x >> 6, lane = threadIdx.x & 63;
  const int row = blockIdx.x * 4 + wave;                 // 0..1023
  const size_t rb = (size_t)row * CP;
  if (row >= HCN_) {
    c1[rb + lane] = (_Float16)0.f;       c2[rb + lane] = (_Float16)0.f;
    c1[rb + lane + 64] = (_Float16)0.f;  c2[rb + lane + 64] = (_Float16)0.f;
    c1[rb + lane + 128] = (_Float16)0.f; c2[rb + lane + 128] = (_Float16)0.f;
    if (lane < 32) { c1[rb + 192 + lane] = (_Float16)0.f; c2[rb + 192 + lane] = (_Float16)0.f; }
    return;
  }
  float* br = bl + (size_t)row * L_;
  float x0 = br[lane];
  float x1 = br[lane + 64];
  float x2 = br[lane + 128];
  float x3 = (lane < 8) ? br[lane + 192] : -3.0e38f;
  if (SUM) {
#pragma unroll 8
    for (int s = 0; s < NSLAB; ++s) {
      const float* p = part + ((size_t)s * SROW + row) * SPL;
      x0 += p[lane];
      x1 += p[lane + 64];
      x2 += p[lane + 128];
      if (lane < 8) x3 += p[lane + 192];
    }
    br[lane] = x0; br[lane + 64] = x1; br[lane + 128] = x2;
    if (lane < 8) br[lane + 192] = x3;
  }
  float m = fmaxf(fmaxf(x0, x1), fmaxf(x2, x3));
#pragma unroll
  for (int off = 32; off; off >>= 1) m = fmaxf(m, __shfl_xor(m, off));
  float e0 = expf(x0 - m), e1 = expf(x1 - m), e2 = expf(x2 - m);
  float e3 = (lane < 8) ? expf(x3 - m) : 0.f;
  float ssum = e0 + e1 + e2 + e3;
#pragma unroll
  for (int off = 32; off; off >>= 1) ssum += __shfl_xor(ssum, off);
  float inv = CSC / ssum;
  _Float16 s1, s2;
  split2h(e0 * inv, s1, s2); c1[rb + lane] = s1;       c2[rb + lane] = s2;
  split2h(e1 * inv, s1, s2); c1[rb + lane + 64] = s1;  c2[rb + lane + 64] = s2;
  split2h(e2 * inv, s1, s2); c1[rb + lane + 128] = s1; c2[rb + lane + 128] = s2;
  if (lane < 8) {
    split2h(e3 * inv, s1, s2); c1[rb + 192 + lane] = s1; c2[rb + 192 + lane] = s2;
  } else if (lane < 32) {
    c1[rb + 192 + lane] = (_Float16)0.f; c2[rb + 192 + lane] = (_Float16)0.f;
  }
}

// ---------------------------------------------------------------------------
// k_iter: fused routing iteration, fp16 2-split / 3-pass, pre-scaled.
// Per block: 4 batches x 64 h-rows. LDS 38.9 KB (UN staged in row-groups
// 112+96 under the 20.5 KB UT union) -> 4 blocks/CU resident.
// Grid 1024, decode xcd=id&7, ht=(id>>3)&15, bgH=id>>7, bg=xcd+8*bgH.
// UV partials: plain stores into slab part[bg]. HOUT -> padded bf16 h.
template<int UV, int HOUT>
__global__ __launch_bounds__(256, 4) void k_iter(
    const _Float16* __restrict__ c1p, const _Float16* __restrict__ c2p,
    const _Float16* __restrict__ un1, const _Float16* __restrict__ un2,
    const _Float16* __restrict__ ut1, const _Float16* __restrict__ ut2,
    const float* __restrict__ wdim, const float* __restrict__ bdim,
    float* __restrict__ part, unsigned short* __restrict__ hb) {
  // union region 20,480 B: UT [2][2][64][40] / UN row-group [2][112][40]
  __shared__ __align__(16) _Float16 smem[10240];
  // v_s only exists in the UV variant (t=2 gets ~20.5 KB total -> 6+ blocks/CU)
  __shared__ __align__(16) _Float16 v_sm[UV ? (2 * 64 * 72) : 2];
  typedef _Float16 (*UTarr)[2][64][40];
  typedef _Float16 (*UNarr)[112][40];
  typedef _Float16 (*VSarr)[64][72];
  UTarr UT = reinterpret_cast<UTarr>(smem);
  UNarr UN = reinterpret_cast<UNarr>(smem);
  VSarr VS = reinterpret_cast<VSarr>(v_sm);

  const int id = blockIdx.x;
  const int xcd = id & 7;
  const int ht  = (id >> 3) & 15;
  const int bgH = id >> 7;                      // 0..7
  const int bg  = xcd + (bgH << 3);             // 0..63; bg%8 == id%8 (XCD pin)
  const int h0 = ht * 64;
  const int b0 = bg * 4;
  const int tid = threadIdx.x;
  const int wave = tid >> 6, lane = tid & 63;
  const int l15 = lane & 15, oc = lane >> 4;
  const int rowA = h0 + wave * 16 + l15;     // A-frag row (c row / v row)
  const int rowC = h0 + wave * 16 + oc * 4;  // C/D row base (+r)

#define STAGE_UT(cck, bf) {                                                    \
    const int d_ = tid >> 2, q_ = tid & 3;                                     \
    const size_t so_ = ((size_t)b * HD_ + d_) * CP + (cck) * 32 + q_ * 8;      \
    *(uint4*)&UT[bf][0][d_][q_ * 8] = *(const uint4*)&ut1[so_];                \
    *(uint4*)&UT[bf][1][d_][q_ * 8] = *(const uint4*)&ut2[so_];                \
  }

// stage UN row-group g_ (g0: rows 0..111, g1: rows 112..207) of k-half half_
#define STAGE_UN2(half_, g_, nrows_) {                                        \
    _Pragma("unroll")                                                          \
    for (int j_ = 0; j_ < 2; ++j_) {                                           \
      int t_ = tid + 256 * j_;                                                 \
      if (t_ < (nrows_) * 4) {                                                 \
        int row_ = t_ >> 2, q_ = t_ & 3;                                       \
        const size_t so_ = ((size_t)b * UNR + (g_) * 112 + row_) * HD_         \
                           + (half_) * 32 + q_ * 8;                            \
        *(uint4*)&UN[0][row_][q_ * 8] = *(const uint4*)&un1[so_];              \
        *(uint4*)&UN[1][row_][q_ * 8] = *(const uint4*)&un2[so_];              \
      } } }

  // hoisted A fragments (c rows; invariant over the batches)
  half8 a_f[7][2];
#pragma unroll
  for (int ck = 0; ck < 7; ++ck) {
    const size_t off = (size_t)rowA * CP + ck * 32 + oc * 8;
    a_f[ck][0] = *(const half8*)&c1p[off];
    a_f[ck][1] = *(const half8*)&c2p[off];
  }

  f32x4 acc_uv[13];
  if (UV) {
#pragma unroll
    for (int nt = 0; nt < 13; ++nt) acc_uv[nt] = (f32x4){0.f, 0.f, 0.f, 0.f};
  }
  float wd[4] = {0.f, 0.f, 0.f, 0.f};
  float bd = 0.f;
  if (HOUT) {
#pragma unroll
    for (int nt = 0; nt < 4; ++nt) wd[nt] = wdim[nt * 16 + l15];
    bd = bdim[0];
  }

  for (int bi = 0; bi < 4; ++bi) {
    const int b = b0 + bi;
    // ---------------- SV: s = c @ umap[b] (scaled 2^22) ----------------
    f32x4 acc_s[4];
#pragma unroll
    for (int nt = 0; nt < 4; ++nt) acc_s[nt] = (f32x4){0.f, 0.f, 0.f, 0.f};
    STAGE_UT(0, 0);
    __syncthreads();
#pragma unroll
    for (int ck = 0; ck < 7; ++ck) {
      if (ck < 6) STAGE_UT(ck + 1, (ck + 1) & 1);
      const int cb = ck & 1;
#pragma unroll
      for (int nt = 0; nt < 4; ++nt) {
        const half8 b1 = *(const half8*)&UT[cb][0][nt * 16 + l15][oc * 8];
        const half8 b2 = *(const half8*)&UT[cb][1][nt * 16 + l15][oc * 8];
        THREEPASS(acc_s[nt], a_f[ck][0], a_f[ck][1], b1, b2);
      }
      __syncthreads();
    }
    // ---------------- squash (in-register, descaled) ----------------
    float xdesc[4][4];   // [nt][r]
#pragma unroll
    for (int nt = 0; nt < 4; ++nt)
#pragma unroll
      for (int r = 0; r < 4; ++r) xdesc[nt][r] = acc_s[nt][r] * SV_DESC;
    float gg[4], hq[4];
#pragma unroll
    for (int r = 0; r < 4; ++r) {
      float sq = 0.f, hpp = 0.f;
#pragma unroll
      for (int nt = 0; nt < 4; ++nt) {
        float x = xdesc[nt][r];
        sq += x * x;
        if (HOUT) hpp += x * wd[nt];
      }
#pragma unroll
      for (int off = 8; off; off >>= 1) {
        sq += __shfl_xor(sq, off);
        if (HOUT) hpp += __shfl_xor(hpp, off);
      }
      gg[r] = sq / ((1.f + sq) * sqrtf(sq + EPS_));
      if (HOUT) hq[r] = gg[r] * hpp + bd;
    }
    if (HOUT && l15 == 0) {
      // padded bf16 h write: rows >= 1000 exact zero (rowC is 4-aligned)
      ushort4 hv4;
      if (rowC < HCN_) {
        hv4.x = f2bf(hq[0]); hv4.y = f2bf(hq[1]);
        hv4.z = f2bf(hq[2]); hv4.w = f2bf(hq[3]);
      } else {
        hv4.x = hv4.y = hv4.z = hv4.w = 0;
      }
      *(ushort4*)&hb[(size_t)b * 1024 + rowC] = hv4;
    }
    // ---------------- UV: acc_uv += v @ umap[b]^T ----------------
    if (UV) {
#pragma unroll
      for (int nt = 0; nt < 4; ++nt)
#pragma unroll
        for (int r = 0; r < 4; ++r) {
          _Float16 s1, s2;
          split2h(VSC * gg[r] * xdesc[nt][r], s1, s2);
          const int vr = wave * 16 + oc * 4 + r, vc = nt * 16 + l15;
          VS[0][vr][vc] = s1; VS[1][vr][vc] = s2;
        }
      __syncthreads();   // v_s ready; SV's UT reads all done (region reuse ok)
#pragma unroll
      for (int half = 0; half < 2; ++half) {
        const int vo = half * 32 + oc * 8;
        const half8 av1 = *(const half8*)&VS[0][wave * 16 + l15][vo];
        const half8 av2 = *(const half8*)&VS[1][wave * 16 + l15][vo];
#pragma unroll
        for (int g = 0; g < 2; ++g) {
          STAGE_UN2(half, g, (g ? 96 : 112));
          __syncthreads();            // row-group staged
          if (g == 0) {
#pragma unroll
            for (int nt = 0; nt < 7; ++nt) {
              const half8 b1 = *(const half8*)&UN[0][nt * 16 + l15][oc * 8];
              const half8 b2 = *(const half8*)&UN[1][nt * 16 + l15][oc * 8];
              THREEPASS(acc_uv[nt], av1, av2, b1, b2);
            }
          } else {
#pragma unroll
            for (int nt = 7; nt < 13; ++nt) {
              const half8 b1 = *(const half8*)&UN[0][(nt - 7) * 16 + l15][oc * 8];
              const half8 b2 = *(const half8*)&UN[1][(nt - 7) * 16 + l15][oc * 8];
              THREEPASS(acc_uv[nt], av1, av2, b1, b2);
            }
          }
          __syncthreads();            // row-group consumed
        }
      }
    }
  }
  if (UV) {
    // plain stores into this bg's slab (regions disjoint by (bg,ht))
    float* pp = part + (size_t)bg * SROW * SPL;
#pragma unroll
    for (int nt = 0; nt < 13; ++nt)
#pragma unroll
      for (int r = 0; r < 4; ++r)
        pp[(size_t)(rowC + r) * SPL + nt * 16 + l15] = acc_uv[nt][r] * UV_DESC;
  }
#undef STAGE_UT
#undef STAGE_UN2
}

// ---------------------------------------------------------------------------
// k_out_mfma: out[b,p] = sum_h h[b,h]*w_part[p,h] + b_part[p]  via bf16 MFMA.
#define KPAD 1024
#define LPITCH 72
__global__ __launch_bounds__(512) void k_out_mfma(const unsigned short* __restrict__ hb,
                                                  const float* __restrict__ wpart,
                                                  const float* __restrict__ bpart,
                                                  float* __restrict__ out) {
  __shared__ __align__(16) unsigned short w_lds[128 * LPITCH];  // 18432 B
  __shared__ __align__(16) unsigned short h_lds[128 * LPITCH];  // 18432 B
  const int p0 = blockIdx.x * 128;
  const int b0 = blockIdx.y * 128;
  const int t = threadIdx.x;
  const int wave = t >> 6, lane = t & 63;
  const int nt = wave & 3, mh = wave >> 2;
  const int l31 = lane & 31, lhi = lane >> 5;

  f32x16 acc0 = {};
  f32x16 acc1 = {};

  const int wrow = t >> 2;
  const int wq0  = (t & 3) * 4;
  int prow = p0 + wrow; if (prow > POI_ - 1) prow = POI_ - 1;
  const float* wrp = wpart + (size_t)prow * HCN_;

  for (int ch = 0; ch < 16; ++ch) {
    const int k0 = ch * 64;
    __syncthreads();
#pragma unroll
    for (int qq = 0; qq < 4; ++qq) {
      const int q = wq0 + qq;
      float4 wv;
      if (k0 + q * 4 + 3 < HCN_) {
        wv = *(const float4*)(wrp + k0 + q * 4);
      } else {
        float x0 = (k0 + q * 4 + 0 < HCN_) ? wrp[k0 + q * 4 + 0] : 0.f;
        float x1 = (k0 + q * 4 + 1 < HCN_) ? wrp[k0 + q * 4 + 1] : 0.f;
        float x2 = (k0 + q * 4 + 2 < HCN_) ? wrp[k0 + q * 4 + 2] : 0.f;
        float x3 = (k0 + q * 4 + 3 < HCN_) ? wrp[k0 + q * 4 + 3] : 0.f;
        wv = make_float4(x0, x1, x2, x3);
      }
      ushort4 bv;
      bv.x = f2bf(wv.x); bv.y = f2bf(wv.y); bv.z = f2bf(wv.z); bv.w = f2bf(wv.w);
      *(ushort4*)&w_lds[wrow * LPITCH + q * 4] = bv;
    }
#pragma unroll
    for (int n = 0; n < 2; ++n) {
      const int u = t + n * 512;
      const int hrow = u >> 3, hc = u & 7;
      const uint4 hv = *(const uint4*)(hb + (size_t)(b0 + hrow) * KPAD + k0 + hc * 8);
      *(uint4*)&h_lds[hrow * LPITCH + hc * 8] = hv;
    }
    __syncthreads();
#pragma unroll
    for (int ks = 0; ks < 4; ++ks) {
      const int kc = ks * 16 + lhi * 8;
      bf16x8 bfr = *(const bf16x8*)&w_lds[(nt * 32 + l31) * LPITCH + kc];
      bf16x8 a0  = *(const bf16x8*)&h_lds[(mh * 64 + 0 * 32 + l31) * LPITCH + kc];
      bf16x8 a1  = *(const bf16x8*)&h_lds[(mh * 64 + 1 * 32 + l31) * LPITCH + kc];
      acc0 = __builtin_amdgcn_mfma_f32_32x32x16_bf16(a0, bfr, acc0, 0, 0, 0);
      acc1 = __builtin_amdgcn_mfma_f32_32x32x16_bf16(a1, bfr, acc1, 0, 0, 0);
    }
  }

  const int p = p0 + nt * 32 + l31;
  const bool pok = (p < POI_);
  const float bp = pok ? bpart[p] : 0.f;
#pragma unroll
  for (int m = 0; m < 2; ++m) {
    const f32x16& a = m ? acc1 : acc0;
#pragma unroll
    for (int r = 0; r < 16; ++r) {
      const int brow = b0 + mh * 64 + m * 32 + (r & 3) + 8 * (r >> 2) + 4 * lhi;
      if (pok) out[(size_t)brow * POI_ + p] = a[r] + bp;
    }
  }
}

// ---------------------------------------------------------------------------
extern "C" void kernel_launch(void* const* d_in, const int* in_sizes, int n_in,
                              void* d_out, int out_size, void* d_ws, size_t ws_size,
                              hipStream_t stream) {
  const float* u     = (const float*)d_in[0];
  const float* lmap  = (const float*)d_in[1];
  const float* rw    = (const float*)d_in[2];
  const float* wdim  = (const float*)d_in[3];
  const float* bdim  = (const float*)d_in[4];
  const float* wpart = (const float*)d_in[5];
  const float* bpart = (const float*)d_in[6];
  float* out = (float*)d_out;

  // ---- workspace layout (bytes; ~85 MB total) ----
  char* W = (char*)d_ws;
  float* bl        = (float*)W;      W += 802816;     // [1000][200] f32
  _Float16* c1     = (_Float16*)W;   W += 458752;     // [1024][224]
  _Float16* c2     = (_Float16*)W;   W += 458752;
  _Float16* un1    = (_Float16*)W;   W += 6815744;    // [256][208][64]
  _Float16* un2    = (_Float16*)W;   W += 6815744;
  _Float16* ut1    = (_Float16*)W;   W += 7340032;    // [256][64][224]
  _Float16* ut2    = (_Float16*)W;   W += 7340032;
  unsigned short* h_bf16 = (unsigned short*)W; W += 524288;   // [256][1024]
  float* part      = (float*)W;      W += (size_t)NSLAB * SROW * SPL * 4;  // 54.5 MB
  // umap f32 (13.1 MB) overlaps part: dead after k_prep2, part written later.
  float* umap      = part;

  hipMemcpyAsync(bl, rw, (size_t)HCN_ * L_ * sizeof(float),
                 hipMemcpyDeviceToDevice, stream);
  k_umap<<<1600, 256, 0, stream>>>(u, lmap, umap);
  k_prep2<<<256, 256, 0, stream>>>(umap, un1, un2, ut1, ut2);

  // t = 0: no partials yet
  k_softmax2<0><<<256, 256, 0, stream>>>(bl, part, c1, c2);
  k_iter<1, 0><<<1024, 256, 0, stream>>>(c1, c2, un1, un2, ut1, ut2,
                                         wdim, bdim, part, h_bf16);
  // t = 1: fold in t=0 partials
  k_softmax2<1><<<256, 256, 0, stream>>>(bl, part, c1, c2);
  k_iter<1, 0><<<1024, 256, 0, stream>>>(c1, c2, un1, un2, ut1, ut2,
                                         wdim, bdim, part, h_bf16);
  // t = 2: fold in t=1 partials; emit h, no UV
  k_softmax2<1><<<256, 256, 0, stream>>>(bl, part, c1, c2);
  k_iter<0, 1><<<1024, 256, 0, stream>>>(c1, c2, un1, un2, ut1, ut2,
                                         wdim, bdim, part, h_bf16);

  k_out_mfma<<<dim3(157, 2), 512, 0, stream>>>(h_bf16, wpart, bpart, out);
}

// Round 14
// 380.477 us; speedup vs baseline: 1.5485x; 1.1201x over previous
//
#include <hip/hip_runtime.h>

#define B_    256
#define L_    200
#define EMB_  128
#define HD_   64
#define HCN_  1000
#define POI_  20000
#define EPS_  1e-8f
#define CP    224          // padded L for c / ut k-dim (7 chunks of 32)
#define UNR   208          // umap-native rows (l), rows 200..207 zero
#define NSLAB 64           // per-bg partial slabs (plain stores, disjoint)
#define SROW  1024         // slab row count (padded)
#define SPL   208          // slab l pitch (padded)

// power-of-2 pre-scales keep fp16 second-splits in the normal range
#define CSC   16384.0f     // c scale (2^14)
#define USC   256.0f       // umap scale (2^8)
#define VSC   1024.0f      // v scale (2^10)
#define AUSC  1024.0f      // u scale for k_umap MFMA (2^10)
#define LUSC  1024.0f      // lmap scale for k_umap MFMA (2^10)
#define SV_DESC (1.0f / (CSC * USC))   // 2^-22, exact
#define UV_DESC (1.0f / (VSC * USC))   // 2^-18, exact
#define UM_DESC (1.0f / (AUSC * LUSC)) // 2^-20, exact

typedef _Float16 half8 __attribute__((ext_vector_type(8)));
typedef __bf16  bf16x8 __attribute__((ext_vector_type(8)));
typedef float   f32x4  __attribute__((ext_vector_type(4)));
typedef float   f32x16 __attribute__((ext_vector_type(16)));

__device__ __forceinline__ unsigned short f2bf(float f) {
  union { float f; unsigned int u; } v; v.f = f;
  unsigned int r = (v.u + 0x7FFFu + ((v.u >> 16) & 1u)) >> 16;  // RNE
  return (unsigned short)r;
}
// 2-way fp16 split of a PRE-SCALED value: x ~= s1+s2 to ~2^-22 relative
__device__ __forceinline__ void split2h(float x, _Float16& s1, _Float16& s2) {
  s1 = (_Float16)x;
  s2 = (_Float16)(x - (float)s1);
}

// 3-pass split product: drops s2*t2 (~2^-22 rel, same order as split residual)
#define THREEPASS(acc, A1f, A2f, B1f, B2f)                                 \
  acc = __builtin_amdgcn_mfma_f32_16x16x32_f16(A2f, B1f, acc, 0, 0, 0);    \
  acc = __builtin_amdgcn_mfma_f32_16x16x32_f16(A1f, B2f, acc, 0, 0, 0);    \
  acc = __builtin_amdgcn_mfma_f32_16x16x32_f16(A1f, B1f, acc, 0, 0, 0);

// ---------------------------------------------------------------------------
// k_umap: u_map = u @ l_map_h via split-fp16 3-pass MFMA (round-13 post-mortem:
// shfl+FMA chain version stayed ~90 us latency-bound; MFMA floor ~10 us).
// Precision: 2^-21 rel — same order as the 2-way-split representation error
// already accepted downstream (un/ut). Fragment mapping identical to k_iter.
// Grid 200 x 256 thr (4 waves x 4 tiles of 16 rows each = 3200 tiles).
__global__ __launch_bounds__(256, 2) void k_umap(const float* __restrict__ u,
                                                 const float* __restrict__ lmap,
                                                 float* __restrict__ umap) {
  __shared__ __align__(16) _Float16 lmT[2][64][136];     // 34.8 KB (B: lmap^T splits)
  __shared__ __align__(16) _Float16 uA[4][2][16][136];   // 34.8 KB (A: u-row splits)
  const int tid = threadIdx.x;
  // build lmT from lmap fp32 [128 k][64 d] (transpose + split; once per block)
  for (int i = tid; i < 128 * 64; i += 256) {
    int k = i >> 6, d = i & 63;
    _Float16 s1, s2;
    split2h(lmap[i] * LUSC, s1, s2);
    lmT[0][d][k] = s1;
    lmT[1][d][k] = s2;
  }
  __syncthreads();

  const int wave = tid >> 6, lane = tid & 63;
  const int l15 = lane & 15, oc = lane >> 4;

  for (int t = 0; t < 4; ++t) {
    const int row0 = (blockIdx.x * 16 + wave * 4 + t) * 16;
    // stage this wave's 16 u-rows as fp16 splits (4 lanes per row, 32 f32 each)
    {
      const int r_ = lane >> 2, seg = lane & 3;
      const float* src = u + (size_t)(row0 + r_) * EMB_ + seg * 32;
#pragma unroll
      for (int j = 0; j < 8; ++j) {
        float4 v = *(const float4*)(src + j * 4);
        _Float16 t1[4], t2[4];
        split2h(v.x * AUSC, t1[0], t2[0]);
        split2h(v.y * AUSC, t1[1], t2[1]);
        split2h(v.z * AUSC, t1[2], t2[2]);
        split2h(v.w * AUSC, t1[3], t2[3]);
        const int kb = seg * 32 + j * 4;
        *(uint2*)&uA[wave][0][r_][kb] = *(uint2*)t1;
        *(uint2*)&uA[wave][1][r_][kb] = *(uint2*)t2;
      }
    }
    // wave-local LDS: in-wave DS ordering + compiler lgkmcnt cover the hazard
    f32x4 acc[4] = {};
#pragma unroll
    for (int ck = 0; ck < 4; ++ck) {
      const half8 a1 = *(const half8*)&uA[wave][0][l15][ck * 32 + oc * 8];
      const half8 a2 = *(const half8*)&uA[wave][1][l15][ck * 32 + oc * 8];
#pragma unroll
      for (int nt = 0; nt < 4; ++nt) {
        const half8 b1 = *(const half8*)&lmT[0][nt * 16 + l15][ck * 32 + oc * 8];
        const half8 b2 = *(const half8*)&lmT[1][nt * 16 + l15][ck * 32 + oc * 8];
        THREEPASS(acc[nt], a1, a2, b1, b2);
      }
    }
    // D: row = oc*4 + r, col = nt*16 + l15
#pragma unroll
    for (int nt = 0; nt < 4; ++nt)
#pragma unroll
      for (int r = 0; r < 4; ++r)
        umap[(size_t)(row0 + oc * 4 + r) * HD_ + nt * 16 + l15] = acc[nt][r] * UM_DESC;
  }
}

// ---------------------------------------------------------------------------
// k_prep2: umap[b] fp32 -> fp16 2-splits of (umap*USC), native [b][208][64]
// (rows 200..207 zero) and transposed [b][64][224] (cols 200..223 zero).
__global__ __launch_bounds__(256) void k_prep2(const float* __restrict__ umap,
    _Float16* __restrict__ un1, _Float16* __restrict__ un2,
    _Float16* __restrict__ ut1, _Float16* __restrict__ ut2) {
  __shared__ __align__(16) float us[CP][68];   // 60.9 KB
  const int b = blockIdx.x;
  const float* ub = umap + (size_t)b * L_ * HD_;
  for (int i = threadIdx.x; i < CP * HD_; i += 256) {
    int l = i >> 6, d = i & 63;
    us[l][d] = (l < L_) ? ub[l * HD_ + d] * USC : 0.f;
  }
  __syncthreads();
  // native: (row 208, oct 8)
  for (int s = threadIdx.x; s < UNR * 8; s += 256) {
    int row = s >> 3, oct = s & 7;
    _Float16 t1[8], t2[8];
#pragma unroll
    for (int j = 0; j < 8; ++j) split2h(us[row][oct * 8 + j], t1[j], t2[j]);
    size_t dst = ((size_t)b * UNR + row) * HD_ + oct * 8;
    *(uint4*)&un1[dst] = *(uint4*)t1;
    *(uint4*)&un2[dst] = *(uint4*)t2;
  }
  // transposed: (d 64, l-oct 28)
  for (int s = threadIdx.x; s < HD_ * 28; s += 256) {
    int d = s / 28, lo8 = s % 28;
    _Float16 t1[8], t2[8];
#pragma unroll
    for (int j = 0; j < 8; ++j) split2h(us[lo8 * 8 + j][d], t1[j], t2[j]);
    size_t dst = ((size_t)b * HD_ + d) * CP + lo8 * 8;
    *(uint4*)&ut1[dst] = *(uint4*)t1;
    *(uint4*)&ut2[dst] = *(uint4*)t2;
  }
}

// ---------------------------------------------------------------------------
// k_softmax2: (SUM) fold 64 plain-store slabs into b[row,:] (nontemporal
// reads — slabs are read-once, keep them out of LRU); then softmax ->
// fp16 2-splits of (c*CSC), [1024][224]; pad rows/cols exact zero.
template<int SUM>
__global__ __launch_bounds__(256) void k_softmax2(float* __restrict__ bl,
    const float* __restrict__ part,
    _Float16* __restrict__ c1, _Float16* __restrict__ c2) {
  const int wave = threadIdx.x >> 6, lane = threadIdx.x & 63;
  const int row = blockIdx.x * 4 + wave;                 // 0..1023
  const size_t rb = (size_t)row * CP;
  if (row >= HCN_) {
    c1[rb + lane] = (_Float16)0.f;       c2[rb + lane] = (_Float16)0.f;
    c1[rb + lane + 64] = (_Float16)0.f;  c2[rb + lane + 64] = (_Float16)0.f;
    c1[rb + lane + 128] = (_Float16)0.f; c2[rb + lane + 128] = (_Float16)0.f;
    if (lane < 32) { c1[rb + 192 + lane] = (_Float16)0.f; c2[rb + 192 + lane] = (_Float16)0.f; }
    return;
  }
  float* br = bl + (size_t)row * L_;
  float x0 = br[lane];
  float x1 = br[lane + 64];
  float x2 = br[lane + 128];
  float x3 = (lane < 8) ? br[lane + 192] : -3.0e38f;
  if (SUM) {
#pragma unroll 8
    for (int s = 0; s < NSLAB; ++s) {
      const float* p = part + ((size_t)s * SROW + row) * SPL;
      x0 += __builtin_nontemporal_load(p + lane);
      x1 += __builtin_nontemporal_load(p + lane + 64);
      x2 += __builtin_nontemporal_load(p + lane + 128);
      if (lane < 8) x3 += __builtin_nontemporal_load(p + lane + 192);
    }
    br[lane] = x0; br[lane + 64] = x1; br[lane + 128] = x2;
    if (lane < 8) br[lane + 192] = x3;
  }
  float m = fmaxf(fmaxf(x0, x1), fmaxf(x2, x3));
#pragma unroll
  for (int off = 32; off; off >>= 1) m = fmaxf(m, __shfl_xor(m, off));
  float e0 = expf(x0 - m), e1 = expf(x1 - m), e2 = expf(x2 - m);
  float e3 = (lane < 8) ? expf(x3 - m) : 0.f;
  float ssum = e0 + e1 + e2 + e3;
#pragma unroll
  for (int off = 32; off; off >>= 1) ssum += __shfl_xor(ssum, off);
  float inv = CSC / ssum;
  _Float16 s1, s2;
  split2h(e0 * inv, s1, s2); c1[rb + lane] = s1;       c2[rb + lane] = s2;
  split2h(e1 * inv, s1, s2); c1[rb + lane + 64] = s1;  c2[rb + lane + 64] = s2;
  split2h(e2 * inv, s1, s2); c1[rb + lane + 128] = s1; c2[rb + lane + 128] = s2;
  if (lane < 8) {
    split2h(e3 * inv, s1, s2); c1[rb + 192 + lane] = s1; c2[rb + 192 + lane] = s2;
  } else if (lane < 32) {
    c1[rb + 192 + lane] = (_Float16)0.f; c2[rb + 192 + lane] = (_Float16)0.f;
  }
}

// ---------------------------------------------------------------------------
// k_iter: fused routing iteration, fp16 2-split / 3-pass, pre-scaled.
// Per block: 4 batches x 64 h-rows. LDS 38.9 KB -> 4 blocks/CU resident.
// Grid 1024, decode xcd=id&7, ht=(id>>3)&15, bgH=id>>7, bg=xcd+8*bgH.
// UV partials: NONTEMPORAL row-ordered stores into slab part[bg] (round-13
// post-mortem: normal scattered stores thrashed L2 -> 133 MB HBM writes).
template<int UV, int HOUT>
__global__ __launch_bounds__(256, 4) void k_iter(
    const _Float16* __restrict__ c1p, const _Float16* __restrict__ c2p,
    const _Float16* __restrict__ un1, const _Float16* __restrict__ un2,
    const _Float16* __restrict__ ut1, const _Float16* __restrict__ ut2,
    const float* __restrict__ wdim, const float* __restrict__ bdim,
    float* __restrict__ part, unsigned short* __restrict__ hb) {
  // union region 20,480 B: UT [2][2][64][40] / UN row-group [2][112][40]
  __shared__ __align__(16) _Float16 smem[10240];
  // v_s only exists in the UV variant (t=2 gets ~20.5 KB total -> 6+ blocks/CU)
  __shared__ __align__(16) _Float16 v_sm[UV ? (2 * 64 * 72) : 2];
  typedef _Float16 (*UTarr)[2][64][40];
  typedef _Float16 (*UNarr)[112][40];
  typedef _Float16 (*VSarr)[64][72];
  UTarr UT = reinterpret_cast<UTarr>(smem);
  UNarr UN = reinterpret_cast<UNarr>(smem);
  VSarr VS = reinterpret_cast<VSarr>(v_sm);

  const int id = blockIdx.x;
  const int xcd = id & 7;
  const int ht  = (id >> 3) & 15;
  const int bgH = id >> 7;                      // 0..7
  const int bg  = xcd + (bgH << 3);             // 0..63; bg%8 == id%8 (XCD pin)
  const int h0 = ht * 64;
  const int b0 = bg * 4;
  const int tid = threadIdx.x;
  const int wave = tid >> 6, lane = tid & 63;
  const int l15 = lane & 15, oc = lane >> 4;
  const int rowA = h0 + wave * 16 + l15;     // A-frag row (c row / v row)
  const int rowC = h0 + wave * 16 + oc * 4;  // C/D row base (+r)

#define STAGE_UT(cck, bf) {                                                    \
    const int d_ = tid >> 2, q_ = tid & 3;                                     \
    const size_t so_ = ((size_t)b * HD_ + d_) * CP + (cck) * 32 + q_ * 8;      \
    *(uint4*)&UT[bf][0][d_][q_ * 8] = *(const uint4*)&ut1[so_];                \
    *(uint4*)&UT[bf][1][d_][q_ * 8] = *(const uint4*)&ut2[so_];                \
  }

// stage UN row-group g_ (g0: rows 0..111, g1: rows 112..207) of k-half half_
#define STAGE_UN2(half_, g_, nrows_) {                                        \
    _Pragma("unroll")                                                          \
    for (int j_ = 0; j_ < 2; ++j_) {                                           \
      int t_ = tid + 256 * j_;                                                 \
      if (t_ < (nrows_) * 4) {                                                 \
        int row_ = t_ >> 2, q_ = t_ & 3;                                       \
        const size_t so_ = ((size_t)b * UNR + (g_) * 112 + row_) * HD_         \
                           + (half_) * 32 + q_ * 8;                            \
        *(uint4*)&UN[0][row_][q_ * 8] = *(const uint4*)&un1[so_];              \
        *(uint4*)&UN[1][row_][q_ * 8] = *(const uint4*)&un2[so_];              \
      } } }

  // hoisted A fragments (c rows; invariant over the batches)
  half8 a_f[7][2];
#pragma unroll
  for (int ck = 0; ck < 7; ++ck) {
    const size_t off = (size_t)rowA * CP + ck * 32 + oc * 8;
    a_f[ck][0] = *(const half8*)&c1p[off];
    a_f[ck][1] = *(const half8*)&c2p[off];
  }

  f32x4 acc_uv[13];
  if (UV) {
#pragma unroll
    for (int nt = 0; nt < 13; ++nt) acc_uv[nt] = (f32x4){0.f, 0.f, 0.f, 0.f};
  }
  float wd[4] = {0.f, 0.f, 0.f, 0.f};
  float bd = 0.f;
  if (HOUT) {
#pragma unroll
    for (int nt = 0; nt < 4; ++nt) wd[nt] = wdim[nt * 16 + l15];
    bd = bdim[0];
  }

  for (int bi = 0; bi < 4; ++bi) {
    const int b = b0 + bi;
    // ---------------- SV: s = c @ umap[b] (scaled 2^22) ----------------
    f32x4 acc_s[4];
#pragma unroll
    for (int nt = 0; nt < 4; ++nt) acc_s[nt] = (f32x4){0.f, 0.f, 0.f, 0.f};
    STAGE_UT(0, 0);
    __syncthreads();
#pragma unroll
    for (int ck = 0; ck < 7; ++ck) {
      if (ck < 6) STAGE_UT(ck + 1, (ck + 1) & 1);
      const int cb = ck & 1;
#pragma unroll
      for (int nt = 0; nt < 4; ++nt) {
        const half8 b1 = *(const half8*)&UT[cb][0][nt * 16 + l15][oc * 8];
        const half8 b2 = *(const half8*)&UT[cb][1][nt * 16 + l15][oc * 8];
        THREEPASS(acc_s[nt], a_f[ck][0], a_f[ck][1], b1, b2);
      }
      __syncthreads();
    }
    // ---------------- squash (in-register, descaled) ----------------
    float xdesc[4][4];   // [nt][r]
#pragma unroll
    for (int nt = 0; nt < 4; ++nt)
#pragma unroll
      for (int r = 0; r < 4; ++r) xdesc[nt][r] = acc_s[nt][r] * SV_DESC;
    float gg[4], hq[4];
#pragma unroll
    for (int r = 0; r < 4; ++r) {
      float sq = 0.f, hpp = 0.f;
#pragma unroll
      for (int nt = 0; nt < 4; ++nt) {
        float x = xdesc[nt][r];
        sq += x * x;
        if (HOUT) hpp += x * wd[nt];
      }
#pragma unroll
      for (int off = 8; off; off >>= 1) {
        sq += __shfl_xor(sq, off);
        if (HOUT) hpp += __shfl_xor(hpp, off);
      }
      gg[r] = sq / ((1.f + sq) * sqrtf(sq + EPS_));
      if (HOUT) hq[r] = gg[r] * hpp + bd;
    }
    if (HOUT && l15 == 0) {
      // padded bf16 h write: rows >= 1000 exact zero (rowC is 4-aligned)
      ushort4 hv4;
      if (rowC < HCN_) {
        hv4.x = f2bf(hq[0]); hv4.y = f2bf(hq[1]);
        hv4.z = f2bf(hq[2]); hv4.w = f2bf(hq[3]);
      } else {
        hv4.x = hv4.y = hv4.z = hv4.w = 0;
      }
      *(ushort4*)&hb[(size_t)b * 1024 + rowC] = hv4;
    }
    // ---------------- UV: acc_uv += v @ umap[b]^T ----------------
    if (UV) {
#pragma unroll
      for (int nt = 0; nt < 4; ++nt)
#pragma unroll
        for (int r = 0; r < 4; ++r) {
          _Float16 s1, s2;
          split2h(VSC * gg[r] * xdesc[nt][r], s1, s2);
          const int vr = wave * 16 + oc * 4 + r, vc = nt * 16 + l15;
          VS[0][vr][vc] = s1; VS[1][vr][vc] = s2;
        }
      __syncthreads();   // v_s ready; SV's UT reads all done (region reuse ok)
#pragma unroll
      for (int half = 0; half < 2; ++half) {
        const int vo = half * 32 + oc * 8;
        const half8 av1 = *(const half8*)&VS[0][wave * 16 + l15][vo];
        const half8 av2 = *(const half8*)&VS[1][wave * 16 + l15][vo];
#pragma unroll
        for (int g = 0; g < 2; ++g) {
          STAGE_UN2(half, g, (g ? 96 : 112));
          __syncthreads();            // row-group staged
          if (g == 0) {
#pragma unroll
            for (int nt = 0; nt < 7; ++nt) {
              const half8 b1 = *(const half8*)&UN[0][nt * 16 + l15][oc * 8];
              const half8 b2 = *(const half8*)&UN[1][nt * 16 + l15][oc * 8];
              THREEPASS(acc_uv[nt], av1, av2, b1, b2);
            }
          } else {
#pragma unroll
            for (int nt = 7; nt < 13; ++nt) {
              const half8 b1 = *(const half8*)&UN[0][(nt - 7) * 16 + l15][oc * 8];
              const half8 b2 = *(const half8*)&UN[1][(nt - 7) * 16 + l15][oc * 8];
              THREEPASS(acc_uv[nt], av1, av2, b1, b2);
            }
          }
          __syncthreads();            // row-group consumed
        }
      }
    }
  }
  if (UV) {
    // nontemporal row-ordered stores: each row's 13 x 64B segments issue
    // back-to-back (write-combine), slab lines marked evict-first.
    float* pp = part + (size_t)bg * SROW * SPL;
#pragma unroll
    for (int r = 0; r < 4; ++r) {
      float* rowp = pp + (size_t)(rowC + r) * SPL + l15;
#pragma unroll
      for (int nt = 0; nt < 13; ++nt)
        __builtin_nontemporal_store(acc_uv[nt][r] * UV_DESC, rowp + nt * 16);
    }
  }
#undef STAGE_UT
#undef STAGE_UN2
}

// ---------------------------------------------------------------------------
// k_out_mfma: out[b,p] = sum_h h[b,h]*w_part[p,h] + b_part[p]  via bf16 MFMA.
#define KPAD 1024
#define LPITCH 72
__global__ __launch_bounds__(512) void k_out_mfma(const unsigned short* __restrict__ hb,
                                                  const float* __restrict__ wpart,
                                                  const float* __restrict__ bpart,
                                                  float* __restrict__ out) {
  __shared__ __align__(16) unsigned short w_lds[128 * LPITCH];  // 18432 B
  __shared__ __align__(16) unsigned short h_lds[128 * LPITCH];  // 18432 B
  const int p0 = blockIdx.x * 128;
  const int b0 = blockIdx.y * 128;
  const int t = threadIdx.x;
  const int wave = t >> 6, lane = t & 63;
  const int nt = wave & 3, mh = wave >> 2;
  const int l31 = lane & 31, lhi = lane >> 5;

  f32x16 acc0 = {};
  f32x16 acc1 = {};

  const int wrow = t >> 2;
  const int wq0  = (t & 3) * 4;
  int prow = p0 + wrow; if (prow > POI_ - 1) prow = POI_ - 1;
  const float* wrp = wpart + (size_t)prow * HCN_;

  for (int ch = 0; ch < 16; ++ch) {
    const int k0 = ch * 64;
    __syncthreads();
#pragma unroll
    for (int qq = 0; qq < 4; ++qq) {
      const int q = wq0 + qq;
      float4 wv;
      if (k0 + q * 4 + 3 < HCN_) {
        wv = *(const float4*)(wrp + k0 + q * 4);
      } else {
        float x0 = (k0 + q * 4 + 0 < HCN_) ? wrp[k0 + q * 4 + 0] : 0.f;
        float x1 = (k0 + q * 4 + 1 < HCN_) ? wrp[k0 + q * 4 + 1] : 0.f;
        float x2 = (k0 + q * 4 + 2 < HCN_) ? wrp[k0 + q * 4 + 2] : 0.f;
        float x3 = (k0 + q * 4 + 3 < HCN_) ? wrp[k0 + q * 4 + 3] : 0.f;
        wv = make_float4(x0, x1, x2, x3);
      }
      ushort4 bv;
      bv.x = f2bf(wv.x); bv.y = f2bf(wv.y); bv.z = f2bf(wv.z); bv.w = f2bf(wv.w);
      *(ushort4*)&w_lds[wrow * LPITCH + q * 4] = bv;
    }
#pragma unroll
    for (int n = 0; n < 2; ++n) {
      const int u = t + n * 512;
      const int hrow = u >> 3, hc = u & 7;
      const uint4 hv = *(const uint4*)(hb + (size_t)(b0 + hrow) * KPAD + k0 + hc * 8);
      *(uint4*)&h_lds[hrow * LPITCH + hc * 8] = hv;
    }
    __syncthreads();
#pragma unroll
    for (int ks = 0; ks < 4; ++ks) {
      const int kc = ks * 16 + lhi * 8;
      bf16x8 bfr = *(const bf16x8*)&w_lds[(nt * 32 + l31) * LPITCH + kc];
      bf16x8 a0  = *(const bf16x8*)&h_lds[(mh * 64 + 0 * 32 + l31) * LPITCH + kc];
      bf16x8 a1  = *(const bf16x8*)&h_lds[(mh * 64 + 1 * 32 + l31) * LPITCH + kc];
      acc0 = __builtin_amdgcn_mfma_f32_32x32x16_bf16(a0, bfr, acc0, 0, 0, 0);
      acc1 = __builtin_amdgcn_mfma_f32_32x32x16_bf16(a1, bfr, acc1, 0, 0, 0);
    }
  }

  const int p = p0 + nt * 32 + l31;
  const bool pok = (p < POI_);
  const float bp = pok ? bpart[p] : 0.f;
#pragma unroll
  for (int m = 0; m < 2; ++m) {
    const f32x16& a = m ? acc1 : acc0;
#pragma unroll
    for (int r = 0; r < 16; ++r) {
      const int brow = b0 + mh * 64 + m * 32 + (r & 3) + 8 * (r >> 2) + 4 * lhi;
      if (pok) out[(size_t)brow * POI_ + p] = a[r] + bp;
    }
  }
}

// ---------------------------------------------------------------------------
extern "C" void kernel_launch(void* const* d_in, const int* in_sizes, int n_in,
                              void* d_out, int out_size, void* d_ws, size_t ws_size,
                              hipStream_t stream) {
  const float* u     = (const float*)d_in[0];
  const float* lmap  = (const float*)d_in[1];
  const float* rw    = (const float*)d_in[2];
  const float* wdim  = (const float*)d_in[3];
  const float* bdim  = (const float*)d_in[4];
  const float* wpart = (const float*)d_in[5];
  const float* bpart = (const float*)d_in[6];
  float* out = (float*)d_out;

  // ---- workspace layout (bytes; ~85 MB total) ----
  char* W = (char*)d_ws;
  float* bl        = (float*)W;      W += 802816;     // [1000][200] f32
  _Float16* c1     = (_Float16*)W;   W += 458752;     // [1024][224]
  _Float16* c2     = (_Float16*)W;   W += 458752;
  _Float16* un1    = (_Float16*)W;   W += 6815744;    // [256][208][64]
  _Float16* un2    = (_Float16*)W;   W += 6815744;
  _Float16* ut1    = (_Float16*)W;   W += 7340032;    // [256][64][224]
  _Float16* ut2    = (_Float16*)W;   W += 7340032;
  unsigned short* h_bf16 = (unsigned short*)W; W += 524288;   // [256][1024]
  float* part      = (float*)W;      W += (size_t)NSLAB * SROW * SPL * 4;  // 54.5 MB
  // umap f32 (13.1 MB) overlaps part: dead after k_prep2, part written later.
  float* umap      = part;

  hipMemcpyAsync(bl, rw, (size_t)HCN_ * L_ * sizeof(float),
                 hipMemcpyDeviceToDevice, stream);
  k_umap<<<200, 256, 0, stream>>>(u, lmap, umap);
  k_prep2<<<256, 256, 0, stream>>>(umap, un1, un2, ut1, ut2);

  // t = 0: no partials yet
  k_softmax2<0><<<256, 256, 0, stream>>>(bl, part, c1, c2);
  k_iter<1, 0><<<1024, 256, 0, stream>>>(c1, c2, un1, un2, ut1, ut2,
                                         wdim, bdim, part, h_bf16);
  // t = 1: fold in t=0 partials
  k_softmax2<1><<<256, 256, 0, stream>>>(bl, part, c1, c2);
  k_iter<1, 0><<<1024, 256, 0, stream>>>(c1, c2, un1, un2, ut1, ut2,
                                         wdim, bdim, part, h_bf16);
  // t = 2: fold in t=1 partials; emit h, no UV
  k_softmax2<1><<<256, 256, 0, stream>>>(bl, part, c1, c2);
  k_iter<0, 1><<<1024, 256, 0, stream>>>(c1, c2, un1, un2, ut1, ut2,
                                         wdim, bdim, part, h_bf16);

  k_out_mfma<<<dim3(157, 2), 512, 0, stream>>>(h_bf16, wpart, bpart, out);
}

// Round 15
// 365.962 us; speedup vs baseline: 1.6099x; 1.0397x over previous
//
#include <hip/hip_runtime.h>

#define B_    256
#define L_    200
#define EMB_  128
#define HD_   64
#define HCN_  1000
#define POI_  20000
#define EPS_  1e-8f
#define CP    224          // padded L for c / ut k-dim (7 chunks of 32)
#define UNR   208          // umap-native rows (l), rows 200..207 zero
#define NSLAB 32           // per-bg partial slabs (plain stores, disjoint)
#define SROW  1024         // slab row count (padded)
#define SPL   208          // slab l pitch (padded)

// power-of-2 pre-scales keep fp16 second-splits in the normal range
#define CSC   16384.0f     // c scale (2^14)
#define USC   256.0f       // umap scale (2^8)
#define VSC   1024.0f      // v scale (2^10)
#define AUSC  1024.0f      // u scale for k_umap MFMA (2^10)
#define LUSC  1024.0f      // lmap scale for k_umap MFMA (2^10)
#define SV_DESC (1.0f / (CSC * USC))   // 2^-22, exact
#define UV_DESC (1.0f / (VSC * USC))   // 2^-18, exact
#define UM_DESC (1.0f / (AUSC * LUSC)) // 2^-20, exact

typedef _Float16 half8 __attribute__((ext_vector_type(8)));
typedef __bf16  bf16x8 __attribute__((ext_vector_type(8)));
typedef float   f32x4  __attribute__((ext_vector_type(4)));
typedef float   f32x16 __attribute__((ext_vector_type(16)));

__device__ __forceinline__ unsigned short f2bf(float f) {
  union { float f; unsigned int u; } v; v.f = f;
  unsigned int r = (v.u + 0x7FFFu + ((v.u >> 16) & 1u)) >> 16;  // RNE
  return (unsigned short)r;
}
// 2-way fp16 split of a PRE-SCALED value: x ~= s1+s2 to ~2^-22 relative
__device__ __forceinline__ void split2h(float x, _Float16& s1, _Float16& s2) {
  s1 = (_Float16)x;
  s2 = (_Float16)(x - (float)s1);
}

// 3-pass split product: drops s2*t2 (~2^-22 rel, same order as split residual)
#define THREEPASS(acc, A1f, A2f, B1f, B2f)                                 \
  acc = __builtin_amdgcn_mfma_f32_16x16x32_f16(A2f, B1f, acc, 0, 0, 0);    \
  acc = __builtin_amdgcn_mfma_f32_16x16x32_f16(A1f, B2f, acc, 0, 0, 0);    \
  acc = __builtin_amdgcn_mfma_f32_16x16x32_f16(A1f, B1f, acc, 0, 0, 0);

// ---------------------------------------------------------------------------
// k_umap: u_map = u @ l_map_h via split-fp16 3-pass MFMA.
__global__ __launch_bounds__(256, 2) void k_umap(const float* __restrict__ u,
                                                 const float* __restrict__ lmap,
                                                 float* __restrict__ umap) {
  __shared__ __align__(16) _Float16 lmT[2][64][136];     // 34.8 KB (B: lmap^T splits)
  __shared__ __align__(16) _Float16 uA[4][2][16][136];   // 34.8 KB (A: u-row splits)
  const int tid = threadIdx.x;
  for (int i = tid; i < 128 * 64; i += 256) {
    int k = i >> 6, d = i & 63;
    _Float16 s1, s2;
    split2h(lmap[i] * LUSC, s1, s2);
    lmT[0][d][k] = s1;
    lmT[1][d][k] = s2;
  }
  __syncthreads();

  const int wave = tid >> 6, lane = tid & 63;
  const int l15 = lane & 15, oc = lane >> 4;

  for (int t = 0; t < 4; ++t) {
    const int row0 = (blockIdx.x * 16 + wave * 4 + t) * 16;
    {
      const int r_ = lane >> 2, seg = lane & 3;
      const float* src = u + (size_t)(row0 + r_) * EMB_ + seg * 32;
#pragma unroll
      for (int j = 0; j < 8; ++j) {
        float4 v = *(const float4*)(src + j * 4);
        _Float16 t1[4], t2[4];
        split2h(v.x * AUSC, t1[0], t2[0]);
        split2h(v.y * AUSC, t1[1], t2[1]);
        split2h(v.z * AUSC, t1[2], t2[2]);
        split2h(v.w * AUSC, t1[3], t2[3]);
        const int kb = seg * 32 + j * 4;
        *(uint2*)&uA[wave][0][r_][kb] = *(uint2*)t1;
        *(uint2*)&uA[wave][1][r_][kb] = *(uint2*)t2;
      }
    }
    f32x4 acc[4] = {};
#pragma unroll
    for (int ck = 0; ck < 4; ++ck) {
      const half8 a1 = *(const half8*)&uA[wave][0][l15][ck * 32 + oc * 8];
      const half8 a2 = *(const half8*)&uA[wave][1][l15][ck * 32 + oc * 8];
#pragma unroll
      for (int nt = 0; nt < 4; ++nt) {
        const half8 b1 = *(const half8*)&lmT[0][nt * 16 + l15][ck * 32 + oc * 8];
        const half8 b2 = *(const half8*)&lmT[1][nt * 16 + l15][ck * 32 + oc * 8];
        THREEPASS(acc[nt], a1, a2, b1, b2);
      }
    }
#pragma unroll
    for (int nt = 0; nt < 4; ++nt)
#pragma unroll
      for (int r = 0; r < 4; ++r)
        umap[(size_t)(row0 + oc * 4 + r) * HD_ + nt * 16 + l15] = acc[nt][r] * UM_DESC;
  }
}

// ---------------------------------------------------------------------------
// k_prep2: umap[b] fp32 -> fp16 2-splits of (umap*USC), native [b][208][64]
// (rows 200..207 zero) and transposed [b][64][224] (cols 200..223 zero).
__global__ __launch_bounds__(256) void k_prep2(const float* __restrict__ umap,
    _Float16* __restrict__ un1, _Float16* __restrict__ un2,
    _Float16* __restrict__ ut1, _Float16* __restrict__ ut2) {
  __shared__ __align__(16) float us[CP][68];   // 60.9 KB
  const int b = blockIdx.x;
  const float* ub = umap + (size_t)b * L_ * HD_;
  for (int i = threadIdx.x; i < CP * HD_; i += 256) {
    int l = i >> 6, d = i & 63;
    us[l][d] = (l < L_) ? ub[l * HD_ + d] * USC : 0.f;
  }
  __syncthreads();
  for (int s = threadIdx.x; s < UNR * 8; s += 256) {
    int row = s >> 3, oct = s & 7;
    _Float16 t1[8], t2[8];
#pragma unroll
    for (int j = 0; j < 8; ++j) split2h(us[row][oct * 8 + j], t1[j], t2[j]);
    size_t dst = ((size_t)b * UNR + row) * HD_ + oct * 8;
    *(uint4*)&un1[dst] = *(uint4*)t1;
    *(uint4*)&un2[dst] = *(uint4*)t2;
  }
  for (int s = threadIdx.x; s < HD_ * 28; s += 256) {
    int d = s / 28, lo8 = s % 28;
    _Float16 t1[8], t2[8];
#pragma unroll
    for (int j = 0; j < 8; ++j) split2h(us[lo8 * 8 + j][d], t1[j], t2[j]);
    size_t dst = ((size_t)b * HD_ + d) * CP + lo8 * 8;
    *(uint4*)&ut1[dst] = *(uint4*)t1;
    *(uint4*)&ut2[dst] = *(uint4*)t2;
  }
}

// ---------------------------------------------------------------------------
// k_softmax2: (SUM) fold 32 plain-store slabs into b[row,:] (nontemporal
// reads); then softmax -> fp16 2-splits of (c*CSC), [1024][224].
template<int SUM>
__global__ __launch_bounds__(256) void k_softmax2(float* __restrict__ bl,
    const float* __restrict__ part,
    _Float16* __restrict__ c1, _Float16* __restrict__ c2) {
  const int wave = threadIdx.x >> 6, lane = threadIdx.x & 63;
  const int row = blockIdx.x * 4 + wave;                 // 0..1023
  const size_t rb = (size_t)row * CP;
  if (row >= HCN_) {
    c1[rb + lane] = (_Float16)0.f;       c2[rb + lane] = (_Float16)0.f;
    c1[rb + lane + 64] = (_Float16)0.f;  c2[rb + lane + 64] = (_Float16)0.f;
    c1[rb + lane + 128] = (_Float16)0.f; c2[rb + lane + 128] = (_Float16)0.f;
    if (lane < 32) { c1[rb + 192 + lane] = (_Float16)0.f; c2[rb + 192 + lane] = (_Float16)0.f; }
    return;
  }
  float* br = bl + (size_t)row * L_;
  float x0 = br[lane];
  float x1 = br[lane + 64];
  float x2 = br[lane + 128];
  float x3 = (lane < 8) ? br[lane + 192] : -3.0e38f;
  if (SUM) {
#pragma unroll 8
    for (int s = 0; s < NSLAB; ++s) {
      const float* p = part + ((size_t)s * SROW + row) * SPL;
      x0 += __builtin_nontemporal_load(p + lane);
      x1 += __builtin_nontemporal_load(p + lane + 64);
      x2 += __builtin_nontemporal_load(p + lane + 128);
      if (lane < 8) x3 += __builtin_nontemporal_load(p + lane + 192);
    }
    br[lane] = x0; br[lane + 64] = x1; br[lane + 128] = x2;
    if (lane < 8) br[lane + 192] = x3;
  }
  float m = fmaxf(fmaxf(x0, x1), fmaxf(x2, x3));
#pragma unroll
  for (int off = 32; off; off >>= 1) m = fmaxf(m, __shfl_xor(m, off));
  float e0 = expf(x0 - m), e1 = expf(x1 - m), e2 = expf(x2 - m);
  float e3 = (lane < 8) ? expf(x3 - m) : 0.f;
  float ssum = e0 + e1 + e2 + e3;
#pragma unroll
  for (int off = 32; off; off >>= 1) ssum += __shfl_xor(ssum, off);
  float inv = CSC / ssum;
  _Float16 s1, s2;
  split2h(e0 * inv, s1, s2); c1[rb + lane] = s1;       c2[rb + lane] = s2;
  split2h(e1 * inv, s1, s2); c1[rb + lane + 64] = s1;  c2[rb + lane + 64] = s2;
  split2h(e2 * inv, s1, s2); c1[rb + lane + 128] = s1; c2[rb + lane + 128] = s2;
  if (lane < 8) {
    split2h(e3 * inv, s1, s2); c1[rb + 192 + lane] = s1; c2[rb + 192 + lane] = s2;
  } else if (lane < 32) {
    c1[rb + 192 + lane] = (_Float16)0.f; c2[rb + 192 + lane] = (_Float16)0.f;
  }
}

// ---------------------------------------------------------------------------
// k_iter: fused routing iteration, fp16 2-split / 3-pass, pre-scaled.
// 512 threads, 8 waves: hsub=w&3 (16-row h-tile of 64), ksub=w>>2 (d-half for
// SV, nt-range for UV). Per block: 8 batches x 64 h-rows -> 32 slabs (half
// the partial-reduction traffic of the 4-batch version). Cross-wave squash
// via sqx/hpx LDS exchange. Grid 512 = 32 bg x 16 ht, XCD-pinned (bg%8=id%8).
template<int UV, int HOUT>
__global__ __launch_bounds__(512, 4) void k_iter(
    const _Float16* __restrict__ c1p, const _Float16* __restrict__ c2p,
    const _Float16* __restrict__ un1, const _Float16* __restrict__ un2,
    const _Float16* __restrict__ ut1, const _Float16* __restrict__ ut2,
    const float* __restrict__ wdim, const float* __restrict__ bdim,
    float* __restrict__ part, unsigned short* __restrict__ hb) {
  // union region 33,280 B: UT [2buf][2][64][40] (20.5K) / UN [2][208][40] (33.3K)
  __shared__ __align__(16) _Float16 smem[16640];
  __shared__ __align__(16) _Float16 v_sm[UV ? (2 * 64 * 72) : 2];  // 18.4 KB
  __shared__ __align__(16) float sqx[2][64];
  __shared__ __align__(16) float hpx[2][64];
  typedef _Float16 (*UTarr)[2][64][40];
  typedef _Float16 (*UNarr)[208][40];
  typedef _Float16 (*VSarr)[64][72];
  UTarr UT = reinterpret_cast<UTarr>(smem);
  UNarr UN = reinterpret_cast<UNarr>(smem);
  VSarr VS = reinterpret_cast<VSarr>(v_sm);

  const int id = blockIdx.x;
  const int xcd = id & 7;
  const int ht  = (id >> 3) & 15;
  const int bgH = id >> 7;                      // 0..3
  const int bg  = xcd + (bgH << 3);             // 0..31; bg%8 == id%8 (XCD pin)
  const int h0 = ht * 64;
  const int b0 = bg * 8;
  const int tid = threadIdx.x;
  const int wave = tid >> 6, lane = tid & 63;
  const int hsub = wave & 3, ksub = wave >> 2;
  const int l15 = lane & 15, oc = lane >> 4;
  const int rowA = h0 + hsub * 16 + l15;        // A-frag row (c row / v row)
  const int rowL = hsub * 16 + oc * 4;          // local D row base (+r)
  const int rowC = h0 + rowL;

#define STAGE_UT(cck, bf) {                                                    \
    const int sp_ = tid >> 8, d_ = (tid >> 2) & 63, q_ = tid & 3;              \
    const _Float16* s_ = sp_ ? ut2 : ut1;                                      \
    *(uint4*)&UT[bf][sp_][d_][q_ * 8] =                                        \
      *(const uint4*)&s_[((size_t)b * HD_ + d_) * CP + (cck) * 32 + q_ * 8];   \
  }

#define STAGE_UN(half_) {                                                      \
    _Pragma("unroll")                                                          \
    for (int j_ = 0; j_ < 2; ++j_) {                                           \
      int t_ = tid + 512 * j_;                                                 \
      if (t_ < 832) {                                                          \
        int row_ = t_ >> 2, q_ = t_ & 3;                                       \
        const size_t so_ = ((size_t)b * UNR + row_) * HD_ + (half_) * 32 + q_ * 8; \
        *(uint4*)&UN[0][row_][q_ * 8] = *(const uint4*)&un1[so_];              \
        *(uint4*)&UN[1][row_][q_ * 8] = *(const uint4*)&un2[so_];              \
      } } }

  // hoisted A fragments (c rows; invariant over the batches)
  half8 a_f[7][2];
#pragma unroll
  for (int ck = 0; ck < 7; ++ck) {
    const size_t off = (size_t)rowA * CP + ck * 32 + oc * 8;
    a_f[ck][0] = *(const half8*)&c1p[off];
    a_f[ck][1] = *(const half8*)&c2p[off];
  }

  f32x4 acc_uv[7];
  if (UV) {
#pragma unroll
    for (int nt = 0; nt < 7; ++nt) acc_uv[nt] = (f32x4){0.f, 0.f, 0.f, 0.f};
  }
  float wd[2] = {0.f, 0.f};
  float bd = 0.f;
  if (HOUT) {
#pragma unroll
    for (int j = 0; j < 2; ++j) wd[j] = wdim[(ksub * 2 + j) * 16 + l15];
    bd = bdim[0];
  }

  for (int bi = 0; bi < 8; ++bi) {
    const int b = b0 + bi;
    // ---------------- SV: s = c @ umap[b] (scaled 2^22) ----------------
    f32x4 acc_s[2];
#pragma unroll
    for (int j = 0; j < 2; ++j) acc_s[j] = (f32x4){0.f, 0.f, 0.f, 0.f};
    STAGE_UT(0, 0);
    __syncthreads();                             // B0: UT buf0 ready
#pragma unroll
    for (int ck = 0; ck < 7; ++ck) {
      if (ck < 6) STAGE_UT(ck + 1, (ck + 1) & 1);
      const int cb = ck & 1;
#pragma unroll
      for (int j = 0; j < 2; ++j) {
        const half8 b1 = *(const half8*)&UT[cb][0][(ksub * 2 + j) * 16 + l15][oc * 8];
        const half8 b2 = *(const half8*)&UT[cb][1][(ksub * 2 + j) * 16 + l15][oc * 8];
        THREEPASS(acc_s[j], a_f[ck][0], a_f[ck][1], b1, b2);
      }
      __syncthreads();                           // per-ck barrier
    }
    // ---------------- squash (cross-wave d-half exchange) ----------------
    float xd[2][4];
#pragma unroll
    for (int j = 0; j < 2; ++j)
#pragma unroll
      for (int r = 0; r < 4; ++r) xd[j][r] = acc_s[j][r] * SV_DESC;
    float sqp[4], hpp[4];
#pragma unroll
    for (int r = 0; r < 4; ++r) {
      float sq = xd[0][r] * xd[0][r] + xd[1][r] * xd[1][r];
      float hp = 0.f;
      if (HOUT) hp = xd[0][r] * wd[0] + xd[1][r] * wd[1];
#pragma unroll
      for (int off = 8; off; off >>= 1) {
        sq += __shfl_xor(sq, off);
        if (HOUT) hp += __shfl_xor(hp, off);
      }
      sqp[r] = sq;
      hpp[r] = hp;
    }
    if (l15 == 0) {
#pragma unroll
      for (int r = 0; r < 4; ++r) {
        sqx[ksub][rowL + r] = sqp[r];
        if (HOUT) hpx[ksub][rowL + r] = hpp[r];
      }
    }
    if (UV) STAGE_UN(0);                         // overlap with exchange
    __syncthreads();                             // B1: sqx/hpx + UN half0 ready
    float gg[4], hq[4];
#pragma unroll
    for (int r = 0; r < 4; ++r) {
      float st = sqp[r] + sqx[1 - ksub][rowL + r];
      gg[r] = st / ((1.f + st) * sqrtf(st + EPS_));
      if (HOUT) hq[r] = gg[r] * (hpp[r] + hpx[1 - ksub][rowL + r]) + bd;
    }
    if (HOUT && ksub == 0 && l15 == 0) {
      ushort4 hv4;
      if (rowC < HCN_) {
        hv4.x = f2bf(hq[0]); hv4.y = f2bf(hq[1]);
        hv4.z = f2bf(hq[2]); hv4.w = f2bf(hq[3]);
      } else {
        hv4.x = hv4.y = hv4.z = hv4.w = 0;
      }
      *(ushort4*)&hb[(size_t)b * 1024 + rowC] = hv4;
    }
    // ---------------- UV: acc_uv += v @ umap[b]^T ----------------
    if (UV) {
#pragma unroll
      for (int j = 0; j < 2; ++j)
#pragma unroll
        for (int r = 0; r < 4; ++r) {
          _Float16 s1, s2;
          split2h(VSC * gg[r] * xd[j][r], s1, s2);
          const int vr = rowL + r, vc = (ksub * 2 + j) * 16 + l15;
          VS[0][vr][vc] = s1; VS[1][vr][vc] = s2;
        }
      __syncthreads();                           // B2: VS ready
#pragma unroll
      for (int half = 0; half < 2; ++half) {
        if (half == 1) {
          __syncthreads();                       // B3: UN half0 consumed
          STAGE_UN(1);
          __syncthreads();                       // B4: UN half1 ready
        }
        const int vo = half * 32 + oc * 8;
        const half8 av1 = *(const half8*)&VS[0][hsub * 16 + l15][vo];
        const half8 av2 = *(const half8*)&VS[1][hsub * 16 + l15][vo];
#pragma unroll
        for (int nt = 0; nt < 7; ++nt) {
          int urow = (nt + ksub * 7) * 16 + l15;
          if (urow > 207) urow = 207;            // ksub=1,nt=6: unused lane-safe read
          const half8 b1 = *(const half8*)&UN[0][urow][oc * 8];
          const half8 b2 = *(const half8*)&UN[1][urow][oc * 8];
          THREEPASS(acc_uv[nt], av1, av2, b1, b2);
        }
      }
      __syncthreads();                           // B5: UN consumed; next batch safe
    }
  }
  if (UV) {
    // plain nontemporal stores; block covers rows h0..h0+63 x l 0..207 once.
    float* pp = part + (size_t)bg * SROW * SPL;
#pragma unroll
    for (int r = 0; r < 4; ++r) {
      float* rowp = pp + (size_t)(rowC + r) * SPL + ksub * 112 + l15;
#pragma unroll
      for (int nt = 0; nt < 7; ++nt)
        if (nt + ksub * 7 <= 12)
          __builtin_nontemporal_store(acc_uv[nt][r] * UV_DESC, rowp + nt * 16);
    }
  }
#undef STAGE_UT
#undef STAGE_UN
}

// ---------------------------------------------------------------------------
// k_out_mfma: out[b,p] = sum_h h[b,h]*w_part[p,h] + b_part[p]  via bf16 MFMA.
#define KPAD 1024
#define LPITCH 72
__global__ __launch_bounds__(512) void k_out_mfma(const unsigned short* __restrict__ hb,
                                                  const float* __restrict__ wpart,
                                                  const float* __restrict__ bpart,
                                                  float* __restrict__ out) {
  __shared__ __align__(16) unsigned short w_lds[128 * LPITCH];  // 18432 B
  __shared__ __align__(16) unsigned short h_lds[128 * LPITCH];  // 18432 B
  const int p0 = blockIdx.x * 128;
  const int b0 = blockIdx.y * 128;
  const int t = threadIdx.x;
  const int wave = t >> 6, lane = t & 63;
  const int nt = wave & 3, mh = wave >> 2;
  const int l31 = lane & 31, lhi = lane >> 5;

  f32x16 acc0 = {};
  f32x16 acc1 = {};

  const int wrow = t >> 2;
  const int wq0  = (t & 3) * 4;
  int prow = p0 + wrow; if (prow > POI_ - 1) prow = POI_ - 1;
  const float* wrp = wpart + (size_t)prow * HCN_;

  for (int ch = 0; ch < 16; ++ch) {
    const int k0 = ch * 64;
    __syncthreads();
#pragma unroll
    for (int qq = 0; qq < 4; ++qq) {
      const int q = wq0 + qq;
      float4 wv;
      if (k0 + q * 4 + 3 < HCN_) {
        wv = *(const float4*)(wrp + k0 + q * 4);
      } else {
        float x0 = (k0 + q * 4 + 0 < HCN_) ? wrp[k0 + q * 4 + 0] : 0.f;
        float x1 = (k0 + q * 4 + 1 < HCN_) ? wrp[k0 + q * 4 + 1] : 0.f;
        float x2 = (k0 + q * 4 + 2 < HCN_) ? wrp[k0 + q * 4 + 2] : 0.f;
        float x3 = (k0 + q * 4 + 3 < HCN_) ? wrp[k0 + q * 4 + 3] : 0.f;
        wv = make_float4(x0, x1, x2, x3);
      }
      ushort4 bv;
      bv.x = f2bf(wv.x); bv.y = f2bf(wv.y); bv.z = f2bf(wv.z); bv.w = f2bf(wv.w);
      *(ushort4*)&w_lds[wrow * LPITCH + q * 4] = bv;
    }
#pragma unroll
    for (int n = 0; n < 2; ++n) {
      const int u = t + n * 512;
      const int hrow = u >> 3, hc = u & 7;
      const uint4 hv = *(const uint4*)(hb + (size_t)(b0 + hrow) * KPAD + k0 + hc * 8);
      *(uint4*)&h_lds[hrow * LPITCH + hc * 8] = hv;
    }
    __syncthreads();
#pragma unroll
    for (int ks = 0; ks < 4; ++ks) {
      const int kc = ks * 16 + lhi * 8;
      bf16x8 bfr = *(const bf16x8*)&w_lds[(nt * 32 + l31) * LPITCH + kc];
      bf16x8 a0  = *(const bf16x8*)&h_lds[(mh * 64 + 0 * 32 + l31) * LPITCH + kc];
      bf16x8 a1  = *(const bf16x8*)&h_lds[(mh * 64 + 1 * 32 + l31) * LPITCH + kc];
      acc0 = __builtin_amdgcn_mfma_f32_32x32x16_bf16(a0, bfr, acc0, 0, 0, 0);
      acc1 = __builtin_amdgcn_mfma_f32_32x32x16_bf16(a1, bfr, acc1, 0, 0, 0);
    }
  }

  const int p = p0 + nt * 32 + l31;
  const bool pok = (p < POI_);
  const float bp = pok ? bpart[p] : 0.f;
#pragma unroll
  for (int m = 0; m < 2; ++m) {
    const f32x16& a = m ? acc1 : acc0;
#pragma unroll
    for (int r = 0; r < 16; ++r) {
      const int brow = b0 + mh * 64 + m * 32 + (r & 3) + 8 * (r >> 2) + 4 * lhi;
      if (pok) out[(size_t)brow * POI_ + p] = a[r] + bp;
    }
  }
}

// ---------------------------------------------------------------------------
extern "C" void kernel_launch(void* const* d_in, const int* in_sizes, int n_in,
                              void* d_out, int out_size, void* d_ws, size_t ws_size,
                              hipStream_t stream) {
  const float* u     = (const float*)d_in[0];
  const float* lmap  = (const float*)d_in[1];
  const float* rw    = (const float*)d_in[2];
  const float* wdim  = (const float*)d_in[3];
  const float* bdim  = (const float*)d_in[4];
  const float* wpart = (const float*)d_in[5];
  const float* bpart = (const float*)d_in[6];
  float* out = (float*)d_out;

  // ---- workspace layout (bytes; ~58 MB total) ----
  char* W = (char*)d_ws;
  float* bl        = (float*)W;      W += 802816;     // [1000][200] f32
  _Float16* c1     = (_Float16*)W;   W += 458752;     // [1024][224]
  _Float16* c2     = (_Float16*)W;   W += 458752;
  _Float16* un1    = (_Float16*)W;   W += 6815744;    // [256][208][64]
  _Float16* un2    = (_Float16*)W;   W += 6815744;
  _Float16* ut1    = (_Float16*)W;   W += 7340032;    // [256][64][224]
  _Float16* ut2    = (_Float16*)W;   W += 7340032;
  unsigned short* h_bf16 = (unsigned short*)W; W += 524288;   // [256][1024]
  float* part      = (float*)W;      W += (size_t)NSLAB * SROW * SPL * 4;  // 27.3 MB
  // umap f32 (13.1 MB) overlaps part: dead after k_prep2, part written later.
  float* umap      = part;

  hipMemcpyAsync(bl, rw, (size_t)HCN_ * L_ * sizeof(float),
                 hipMemcpyDeviceToDevice, stream);
  k_umap<<<200, 256, 0, stream>>>(u, lmap, umap);
  k_prep2<<<256, 256, 0, stream>>>(umap, un1, un2, ut1, ut2);

  // t = 0: no partials yet
  k_softmax2<0><<<256, 256, 0, stream>>>(bl, part, c1, c2);
  k_iter<1, 0><<<512, 512, 0, stream>>>(c1, c2, un1, un2, ut1, ut2,
                                        wdim, bdim, part, h_bf16);
  // t = 1: fold in t=0 partials
  k_softmax2<1><<<256, 256, 0, stream>>>(bl, part, c1, c2);
  k_iter<1, 0><<<512, 512, 0, stream>>>(c1, c2, un1, un2, ut1, ut2,
                                        wdim, bdim, part, h_bf16);
  // t = 2: fold in t=1 partials; emit h, no UV
  k_softmax2<1><<<256, 256, 0, stream>>>(bl, part, c1, c2);
  k_iter<0, 1><<<512, 512, 0, stream>>>(c1, c2, un1, un2, ut1, ut2,
                                        wdim, bdim, part, h_bf16);

  k_out_mfma<<<dim3(157, 2), 512, 0, stream>>>(h_bf16, wpart, bpart, out);
}

// Round 16
// 344.675 us; speedup vs baseline: 1.7094x; 1.0618x over previous
//
#include <hip/hip_runtime.h>

#define B_    256
#define L_    200
#define EMB_  128
#define HD_   64
#define HCN_  1000
#define POI_  20000
#define EPS_  1e-8f
#define CP    224          // padded L for c / ut k-dim
#define UNR   208          // umap-native rows (l), rows 200..207 zero
#define NSLAB 64           // per-bg partial slabs (plain stores, disjoint)
#define SROW  1024         // slab row count (padded)
#define SPL   208          // slab l pitch (padded)

// power-of-2 pre-scales keep fp16 second-splits in the normal range
#define CSC   16384.0f     // c scale (2^14)
#define USC   256.0f       // umap scale (2^8)
#define VSC   1024.0f      // v scale (2^10)
#define AUSC  1024.0f      // u scale for k_umap MFMA (2^10)
#define LUSC  1024.0f      // lmap scale for k_umap MFMA (2^10)
#define SV_DESC (1.0f / (CSC * USC))   // 2^-22, exact
#define UV_DESC (1.0f / (VSC * USC))   // 2^-18, exact
#define UM_DESC (1.0f / (AUSC * LUSC)) // 2^-20, exact

typedef _Float16 half8 __attribute__((ext_vector_type(8)));
typedef __bf16  bf16x8 __attribute__((ext_vector_type(8)));
typedef float   f32x4  __attribute__((ext_vector_type(4)));
typedef float   f32x16 __attribute__((ext_vector_type(16)));

__device__ __forceinline__ unsigned short f2bf(float f) {
  union { float f; unsigned int u; } v; v.f = f;
  unsigned int r = (v.u + 0x7FFFu + ((v.u >> 16) & 1u)) >> 16;  // RNE
  return (unsigned short)r;
}
// 2-way fp16 split of a PRE-SCALED value: x ~= s1+s2 to ~2^-22 relative
__device__ __forceinline__ void split2h(float x, _Float16& s1, _Float16& s2) {
  s1 = (_Float16)x;
  s2 = (_Float16)(x - (float)s1);
}

// 3-pass split product: drops s2*t2 (~2^-22 rel, same order as split residual)
#define THREEPASS(acc, A1f, A2f, B1f, B2f)                                 \
  acc = __builtin_amdgcn_mfma_f32_16x16x32_f16(A2f, B1f, acc, 0, 0, 0);    \
  acc = __builtin_amdgcn_mfma_f32_16x16x32_f16(A1f, B2f, acc, 0, 0, 0);    \
  acc = __builtin_amdgcn_mfma_f32_16x16x32_f16(A1f, B1f, acc, 0, 0, 0);

// ---------------------------------------------------------------------------
// k_umap: u_map = u @ l_map_h via split-fp16 3-pass MFMA.
__global__ __launch_bounds__(256, 2) void k_umap(const float* __restrict__ u,
                                                 const float* __restrict__ lmap,
                                                 float* __restrict__ umap) {
  __shared__ __align__(16) _Float16 lmT[2][64][136];     // 34.8 KB (B: lmap^T splits)
  __shared__ __align__(16) _Float16 uA[4][2][16][136];   // 34.8 KB (A: u-row splits)
  const int tid = threadIdx.x;
  for (int i = tid; i < 128 * 64; i += 256) {
    int k = i >> 6, d = i & 63;
    _Float16 s1, s2;
    split2h(lmap[i] * LUSC, s1, s2);
    lmT[0][d][k] = s1;
    lmT[1][d][k] = s2;
  }
  __syncthreads();

  const int wave = tid >> 6, lane = tid & 63;
  const int l15 = lane & 15, oc = lane >> 4;

  for (int t = 0; t < 4; ++t) {
    const int row0 = (blockIdx.x * 16 + wave * 4 + t) * 16;
    {
      const int r_ = lane >> 2, seg = lane & 3;
      const float* src = u + (size_t)(row0 + r_) * EMB_ + seg * 32;
#pragma unroll
      for (int j = 0; j < 8; ++j) {
        float4 v = *(const float4*)(src + j * 4);
        _Float16 t1[4], t2[4];
        split2h(v.x * AUSC, t1[0], t2[0]);
        split2h(v.y * AUSC, t1[1], t2[1]);
        split2h(v.z * AUSC, t1[2], t2[2]);
        split2h(v.w * AUSC, t1[3], t2[3]);
        const int kb = seg * 32 + j * 4;
        *(uint2*)&uA[wave][0][r_][kb] = *(uint2*)t1;
        *(uint2*)&uA[wave][1][r_][kb] = *(uint2*)t2;
      }
    }
    f32x4 acc[4] = {};
#pragma unroll
    for (int ck = 0; ck < 4; ++ck) {
      const half8 a1 = *(const half8*)&uA[wave][0][l15][ck * 32 + oc * 8];
      const half8 a2 = *(const half8*)&uA[wave][1][l15][ck * 32 + oc * 8];
#pragma unroll
      for (int nt = 0; nt < 4; ++nt) {
        const half8 b1 = *(const half8*)&lmT[0][nt * 16 + l15][ck * 32 + oc * 8];
        const half8 b2 = *(const half8*)&lmT[1][nt * 16 + l15][ck * 32 + oc * 8];
        THREEPASS(acc[nt], a1, a2, b1, b2);
      }
    }
#pragma unroll
    for (int nt = 0; nt < 4; ++nt)
#pragma unroll
      for (int r = 0; r < 4; ++r)
        umap[(size_t)(row0 + oc * 4 + r) * HD_ + nt * 16 + l15] = acc[nt][r] * UM_DESC;
  }
}

// ---------------------------------------------------------------------------
// k_prep2: umap[b] fp32 -> fp16 2-splits of (umap*USC), native [b][208][64]
// (rows 200..207 zero) and transposed [b][64][224] (cols 200..223 zero).
__global__ __launch_bounds__(256) void k_prep2(const float* __restrict__ umap,
    _Float16* __restrict__ un1, _Float16* __restrict__ un2,
    _Float16* __restrict__ ut1, _Float16* __restrict__ ut2) {
  __shared__ __align__(16) float us[CP][68];   // 60.9 KB
  const int b = blockIdx.x;
  const float* ub = umap + (size_t)b * L_ * HD_;
  for (int i = threadIdx.x; i < CP * HD_; i += 256) {
    int l = i >> 6, d = i & 63;
    us[l][d] = (l < L_) ? ub[l * HD_ + d] * USC : 0.f;
  }
  __syncthreads();
  for (int s = threadIdx.x; s < UNR * 8; s += 256) {
    int row = s >> 3, oct = s & 7;
    _Float16 t1[8], t2[8];
#pragma unroll
    for (int j = 0; j < 8; ++j) split2h(us[row][oct * 8 + j], t1[j], t2[j]);
    size_t dst = ((size_t)b * UNR + row) * HD_ + oct * 8;
    *(uint4*)&un1[dst] = *(uint4*)t1;
    *(uint4*)&un2[dst] = *(uint4*)t2;
  }
  for (int s = threadIdx.x; s < HD_ * 28; s += 256) {
    int d = s / 28, lo8 = s % 28;
    _Float16 t1[8], t2[8];
#pragma unroll
    for (int j = 0; j < 8; ++j) split2h(us[lo8 * 8 + j][d], t1[j], t2[j]);
    size_t dst = ((size_t)b * HD_ + d) * CP + lo8 * 8;
    *(uint4*)&ut1[dst] = *(uint4*)t1;
    *(uint4*)&ut2[dst] = *(uint4*)t2;
  }
}

// ---------------------------------------------------------------------------
// k_softmax2: (SUM) fold 64 plain-store slabs into b[row,:] (nontemporal
// reads); then softmax -> fp16 2-splits of (c*CSC), [1024][224].
template<int SUM>
__global__ __launch_bounds__(256) void k_softmax2(float* __restrict__ bl,
    const float* __restrict__ part,
    _Float16* __restrict__ c1, _Float16* __restrict__ c2) {
  const int wave = threadIdx.x >> 6, lane = threadIdx.x & 63;
  const int row = blockIdx.x * 4 + wave;                 // 0..1023
  const size_t rb = (size_t)row * CP;
  if (row >= HCN_) {
    c1[rb + lane] = (_Float16)0.f;       c2[rb + lane] = (_Float16)0.f;
    c1[rb + lane + 64] = (_Float16)0.f;  c2[rb + lane + 64] = (_Float16)0.f;
    c1[rb + lane + 128] = (_Float16)0.f; c2[rb + lane + 128] = (_Float16)0.f;
    if (lane < 32) { c1[rb + 192 + lane] = (_Float16)0.f; c2[rb + 192 + lane] = (_Float16)0.f; }
    return;
  }
  float* br = bl + (size_t)row * L_;
  float x0 = br[lane];
  float x1 = br[lane + 64];
  float x2 = br[lane + 128];
  float x3 = (lane < 8) ? br[lane + 192] : -3.0e38f;
  if (SUM) {
#pragma unroll 8
    for (int s = 0; s < NSLAB; ++s) {
      const float* p = part + ((size_t)s * SROW + row) * SPL;
      x0 += __builtin_nontemporal_load(p + lane);
      x1 += __builtin_nontemporal_load(p + lane + 64);
      x2 += __builtin_nontemporal_load(p + lane + 128);
      if (lane < 8) x3 += __builtin_nontemporal_load(p + lane + 192);
    }
    br[lane] = x0; br[lane + 64] = x1; br[lane + 128] = x2;
    if (lane < 8) br[lane + 192] = x3;
  }
  float m = fmaxf(fmaxf(x0, x1), fmaxf(x2, x3));
#pragma unroll
  for (int off = 32; off; off >>= 1) m = fmaxf(m, __shfl_xor(m, off));
  float e0 = expf(x0 - m), e1 = expf(x1 - m), e2 = expf(x2 - m);
  float e3 = (lane < 8) ? expf(x3 - m) : 0.f;
  float ssum = e0 + e1 + e2 + e3;
#pragma unroll
  for (int off = 32; off; off >>= 1) ssum += __shfl_xor(ssum, off);
  float inv = CSC / ssum;
  _Float16 s1, s2;
  split2h(e0 * inv, s1, s2); c1[rb + lane] = s1;       c2[rb + lane] = s2;
  split2h(e1 * inv, s1, s2); c1[rb + lane + 64] = s1;  c2[rb + lane + 64] = s2;
  split2h(e2 * inv, s1, s2); c1[rb + lane + 128] = s1; c2[rb + lane + 128] = s2;
  if (lane < 8) {
    split2h(e3 * inv, s1, s2); c1[rb + 192 + lane] = s1; c2[rb + 192 + lane] = s2;
  } else if (lane < 32) {
    c1[rb + 192 + lane] = (_Float16)0.f; c2[rb + 192 + lane] = (_Float16)0.f;
  }
}

// ---------------------------------------------------------------------------
// k_iter: fused routing iteration, fp16 2-split / 3-pass, pre-scaled.
// Round-16 shape flip: block = 128 h-rows x 4 batches; 8 waves each own
// 16 h-rows x full d=64 (no cross-wave squash). SV staged in K=64 chunks
// (3xK64 + K32 tail): 4 staging barriers/batch with 24 MFMA/wave each;
// UV bursts are 39 MFMA/wave. ~36 barriers/block vs 104 in round 15.
// Grid 512 = 8 ht x 64 bg, XCD-pinned (bg%8 == id%8). Slabs: 64, plain
// nontemporal stores (traffic proven non-limiting in round 15).
template<int UV, int HOUT>
__global__ __launch_bounds__(512, 2) void k_iter(
    const _Float16* __restrict__ c1p, const _Float16* __restrict__ c2p,
    const _Float16* __restrict__ un1, const _Float16* __restrict__ un2,
    const _Float16* __restrict__ ut1, const _Float16* __restrict__ ut2,
    const float* __restrict__ wdim, const float* __restrict__ bdim,
    float* __restrict__ part, unsigned short* __restrict__ hb) {
  // union region 36,864 B: UT [2buf][2sp][64 d][72 k-pitch] / UN [2][208][40]
  __shared__ __align__(16) _Float16 smem[18432];
  __shared__ __align__(16) _Float16 v_sm[UV ? (2 * 128 * 72) : 2];  // 36.9 KB
  typedef _Float16 (*UTarr)[2][64][72];
  typedef _Float16 (*UNarr)[208][40];
  typedef _Float16 (*VSarr)[128][72];
  UTarr UT = reinterpret_cast<UTarr>(smem);
  UNarr UN = reinterpret_cast<UNarr>(smem);
  VSarr VS = reinterpret_cast<VSarr>(v_sm);

  const int id = blockIdx.x;
  const int xcd = id & 7;
  const int ht  = (id >> 3) & 7;                // 0..7 (128-row h tiles)
  const int bgH = id >> 6;                      // 0..7
  const int bg  = xcd + (bgH << 3);             // 0..63; bg%8 == id%8 (XCD pin)
  const int h0 = ht * 128;
  const int b0 = bg * 4;
  const int tid = threadIdx.x;
  const int wave = tid >> 6, lane = tid & 63;
  const int l15 = lane & 15, oc = lane >> 4;
  const int rowA = h0 + wave * 16 + l15;        // A-frag row (c row / v row)
  const int rowL = wave * 16 + oc * 4;          // local D row base (+r), 0..127
  const int rowC = h0 + rowL;

// stage a K=64 ut chunk (cck in 0..2) into buffer bf: 2 x uint4 per thread
#define STAGE_UT64(cck, bf) {                                                  \
    _Pragma("unroll")                                                          \
    for (int j_ = 0; j_ < 2; ++j_) {                                           \
      int s_ = tid + 512 * j_;                                                 \
      int sp_ = s_ >> 9, rem_ = s_ & 511;                                      \
      int d_ = rem_ >> 3, q_ = rem_ & 7;                                       \
      const _Float16* src_ = sp_ ? ut2 : ut1;                                  \
      *(uint4*)&UT[bf][sp_][d_][q_ * 8] =                                      \
        *(const uint4*)&src_[((size_t)b * HD_ + d_) * CP + (cck) * 64 + q_ * 8]; \
    } }

// stage the K=32 tail (k 192..223) into buffer bf: 1 x uint4 per thread
#define STAGE_UT32(bf) {                                                       \
    int sp_ = tid >> 8, rem_ = tid & 255;                                      \
    int d_ = rem_ >> 2, q_ = rem_ & 3;                                         \
    const _Float16* src_ = sp_ ? ut2 : ut1;                                    \
    *(uint4*)&UT[bf][sp_][d_][q_ * 8] =                                        \
      *(const uint4*)&src_[((size_t)b * HD_ + d_) * CP + 192 + q_ * 8];        \
  }

#define STAGE_UN(half_) {                                                      \
    _Pragma("unroll")                                                          \
    for (int j_ = 0; j_ < 2; ++j_) {                                           \
      int t_ = tid + 512 * j_;                                                 \
      if (t_ < 832) {                                                          \
        int row_ = t_ >> 2, q_ = t_ & 3;                                       \
        const size_t so_ = ((size_t)b * UNR + row_) * HD_ + (half_) * 32 + q_ * 8; \
        *(uint4*)&UN[0][row_][q_ * 8] = *(const uint4*)&un1[so_];              \
        *(uint4*)&UN[1][row_][q_ * 8] = *(const uint4*)&un2[so_];              \
      } } }

  // hoisted A fragments (c rows; invariant over the batches)
  half8 a_f[7][2];
#pragma unroll
  for (int ck = 0; ck < 7; ++ck) {
    const size_t off = (size_t)rowA * CP + ck * 32 + oc * 8;
    a_f[ck][0] = *(const half8*)&c1p[off];
    a_f[ck][1] = *(const half8*)&c2p[off];
  }

  f32x4 acc_uv[13];
  if (UV) {
#pragma unroll
    for (int nt = 0; nt < 13; ++nt) acc_uv[nt] = (f32x4){0.f, 0.f, 0.f, 0.f};
  }
  float wd[4] = {0.f, 0.f, 0.f, 0.f};
  float bd = 0.f;
  if (HOUT) {
#pragma unroll
    for (int nt = 0; nt < 4; ++nt) wd[nt] = wdim[nt * 16 + l15];
    bd = bdim[0];
  }

  for (int bi = 0; bi < 4; ++bi) {
    const int b = b0 + bi;
    // ---------------- SV: s = c @ umap[b] (scaled 2^22) ----------------
    f32x4 acc_s[4];
#pragma unroll
    for (int nt = 0; nt < 4; ++nt) acc_s[nt] = (f32x4){0.f, 0.f, 0.f, 0.f};
    STAGE_UT64(0, 0);
    __syncthreads();                             // B0: chunk0 ready
#pragma unroll
    for (int ck = 0; ck < 3; ++ck) {
      if (ck < 2) STAGE_UT64(ck + 1, (ck + 1) & 1)
      else        STAGE_UT32(1)                  // tail -> buf1 (chunk1 consumed)
      const int cb = ck & 1;
#pragma unroll
      for (int nt = 0; nt < 4; ++nt) {
#pragma unroll
        for (int sub = 0; sub < 2; ++sub) {
          const half8 b1 = *(const half8*)&UT[cb][0][nt * 16 + l15][sub * 32 + oc * 8];
          const half8 b2 = *(const half8*)&UT[cb][1][nt * 16 + l15][sub * 32 + oc * 8];
          THREEPASS(acc_s[nt], a_f[ck * 2 + sub][0], a_f[ck * 2 + sub][1], b1, b2);
        }
      }
      __syncthreads();                           // chunk ck+1 / tail ready
    }
    // K32 tail (k 192..223) from buf1
#pragma unroll
    for (int nt = 0; nt < 4; ++nt) {
      const half8 b1 = *(const half8*)&UT[1][0][nt * 16 + l15][oc * 8];
      const half8 b2 = *(const half8*)&UT[1][1][nt * 16 + l15][oc * 8];
      THREEPASS(acc_s[nt], a_f[6][0], a_f[6][1], b1, b2);
    }
    // ---------------- squash (in-register, full d per wave) ----------------
    float xdesc[4][4];
#pragma unroll
    for (int nt = 0; nt < 4; ++nt)
#pragma unroll
      for (int r = 0; r < 4; ++r) xdesc[nt][r] = acc_s[nt][r] * SV_DESC;
    float gg[4], hq[4];
#pragma unroll
    for (int r = 0; r < 4; ++r) {
      float sq = 0.f, hpp = 0.f;
#pragma unroll
      for (int nt = 0; nt < 4; ++nt) {
        float x = xdesc[nt][r];
        sq += x * x;
        if (HOUT) hpp += x * wd[nt];
      }
#pragma unroll
      for (int off = 8; off; off >>= 1) {
        sq += __shfl_xor(sq, off);
        if (HOUT) hpp += __shfl_xor(hpp, off);
      }
      gg[r] = sq / ((1.f + sq) * sqrtf(sq + EPS_));
      if (HOUT) hq[r] = gg[r] * hpp + bd;
    }
    if (HOUT && l15 == 0) {
      ushort4 hv4;
      if (rowC < HCN_) {
        hv4.x = f2bf(hq[0]); hv4.y = f2bf(hq[1]);
        hv4.z = f2bf(hq[2]); hv4.w = f2bf(hq[3]);
      } else {
        hv4.x = hv4.y = hv4.z = hv4.w = 0;
      }
      *(ushort4*)&hb[(size_t)b * 1024 + rowC] = hv4;
    }
    // ---------------- UV: acc_uv += v @ umap[b]^T ----------------
    if (UV) {
#pragma unroll
      for (int nt = 0; nt < 4; ++nt)
#pragma unroll
        for (int r = 0; r < 4; ++r) {
          _Float16 s1, s2;
          split2h(VSC * gg[r] * xdesc[nt][r], s1, s2);
          const int vr = rowL + r, vc = nt * 16 + l15;
          VS[0][vr][vc] = s1; VS[1][vr][vc] = s2;
        }
      __syncthreads();                           // Bvs: VS ready, UT reads done
      STAGE_UN(0);
      __syncthreads();                           // UN half0 ready
      {
        const half8 av1 = *(const half8*)&VS[0][wave * 16 + l15][oc * 8];
        const half8 av2 = *(const half8*)&VS[1][wave * 16 + l15][oc * 8];
#pragma unroll
        for (int nt = 0; nt < 13; ++nt) {
          const half8 b1 = *(const half8*)&UN[0][nt * 16 + l15][oc * 8];
          const half8 b2 = *(const half8*)&UN[1][nt * 16 + l15][oc * 8];
          THREEPASS(acc_uv[nt], av1, av2, b1, b2);
        }
      }
      __syncthreads();                           // half0 consumed
      STAGE_UN(1);
      __syncthreads();                           // half1 ready
      {
        const half8 av1 = *(const half8*)&VS[0][wave * 16 + l15][32 + oc * 8];
        const half8 av2 = *(const half8*)&VS[1][wave * 16 + l15][32 + oc * 8];
#pragma unroll
        for (int nt = 0; nt < 13; ++nt) {
          const half8 b1 = *(const half8*)&UN[0][nt * 16 + l15][oc * 8];
          const half8 b2 = *(const half8*)&UN[1][nt * 16 + l15][oc * 8];
          THREEPASS(acc_uv[nt], av1, av2, b1, b2);
        }
      }
      __syncthreads();                           // UN consumed; next batch safe
    } else {
      __syncthreads();                           // protect UT before restage
    }
  }
  if (UV) {
    // nontemporal row-ordered stores; block covers rows h0..h0+127 once.
    float* pp = part + (size_t)bg * SROW * SPL;
#pragma unroll
    for (int r = 0; r < 4; ++r) {
      float* rowp = pp + (size_t)(rowC + r) * SPL + l15;
#pragma unroll
      for (int nt = 0; nt < 13; ++nt)
        __builtin_nontemporal_store(acc_uv[nt][r] * UV_DESC, rowp + nt * 16);
    }
  }
#undef STAGE_UT64
#undef STAGE_UT32
#undef STAGE_UN
}

// ---------------------------------------------------------------------------
// k_out_mfma: out[b,p] = sum_h h[b,h]*w_part[p,h] + b_part[p]  via bf16 MFMA.
#define KPAD 1024
#define LPITCH 72
__global__ __launch_bounds__(512) void k_out_mfma(const unsigned short* __restrict__ hb,
                                                  const float* __restrict__ wpart,
                                                  const float* __restrict__ bpart,
                                                  float* __restrict__ out) {
  __shared__ __align__(16) unsigned short w_lds[128 * LPITCH];  // 18432 B
  __shared__ __align__(16) unsigned short h_lds[128 * LPITCH];  // 18432 B
  const int p0 = blockIdx.x * 128;
  const int b0 = blockIdx.y * 128;
  const int t = threadIdx.x;
  const int wave = t >> 6, lane = t & 63;
  const int nt = wave & 3, mh = wave >> 2;
  const int l31 = lane & 31, lhi = lane >> 5;

  f32x16 acc0 = {};
  f32x16 acc1 = {};

  const int wrow = t >> 2;
  const int wq0  = (t & 3) * 4;
  int prow = p0 + wrow; if (prow > POI_ - 1) prow = POI_ - 1;
  const float* wrp = wpart + (size_t)prow * HCN_;

  for (int ch = 0; ch < 16; ++ch) {
    const int k0 = ch * 64;
    __syncthreads();
#pragma unroll
    for (int qq = 0; qq < 4; ++qq) {
      const int q = wq0 + qq;
      float4 wv;
      if (k0 + q * 4 + 3 < HCN_) {
        wv = *(const float4*)(wrp + k0 + q * 4);
      } else {
        float x0 = (k0 + q * 4 + 0 < HCN_) ? wrp[k0 + q * 4 + 0] : 0.f;
        float x1 = (k0 + q * 4 + 1 < HCN_) ? wrp[k0 + q * 4 + 1] : 0.f;
        float x2 = (k0 + q * 4 + 2 < HCN_) ? wrp[k0 + q * 4 + 2] : 0.f;
        float x3 = (k0 + q * 4 + 3 < HCN_) ? wrp[k0 + q * 4 + 3] : 0.f;
        wv = make_float4(x0, x1, x2, x3);
      }
      ushort4 bv;
      bv.x = f2bf(wv.x); bv.y = f2bf(wv.y); bv.z = f2bf(wv.z); bv.w = f2bf(wv.w);
      *(ushort4*)&w_lds[wrow * LPITCH + q * 4] = bv;
    }
#pragma unroll
    for (int n = 0; n < 2; ++n) {
      const int u = t + n * 512;
      const int hrow = u >> 3, hc = u & 7;
      const uint4 hv = *(const uint4*)(hb + (size_t)(b0 + hrow) * KPAD + k0 + hc * 8);
      *(uint4*)&h_lds[hrow * LPITCH + hc * 8] = hv;
    }
    __syncthreads();
#pragma unroll
    for (int ks = 0; ks < 4; ++ks) {
      const int kc = ks * 16 + lhi * 8;
      bf16x8 bfr = *(const bf16x8*)&w_lds[(nt * 32 + l31) * LPITCH + kc];
      bf16x8 a0  = *(const bf16x8*)&h_lds[(mh * 64 + 0 * 32 + l31) * LPITCH + kc];
      bf16x8 a1  = *(const bf16x8*)&h_lds[(mh * 64 + 1 * 32 + l31) * LPITCH + kc];
      acc0 = __builtin_amdgcn_mfma_f32_32x32x16_bf16(a0, bfr, acc0, 0, 0, 0);
      acc1 = __builtin_amdgcn_mfma_f32_32x32x16_bf16(a1, bfr, acc1, 0, 0, 0);
    }
  }

  const int p = p0 + nt * 32 + l31;
  const bool pok = (p < POI_);
  const float bp = pok ? bpart[p] : 0.f;
#pragma unroll
  for (int m = 0; m < 2; ++m) {
    const f32x16& a = m ? acc1 : acc0;
#pragma unroll
    for (int r = 0; r < 16; ++r) {
      const int brow = b0 + mh * 64 + m * 32 + (r & 3) + 8 * (r >> 2) + 4 * lhi;
      if (pok) out[(size_t)brow * POI_ + p] = a[r] + bp;
    }
  }
}

// ---------------------------------------------------------------------------
extern "C" void kernel_launch(void* const* d_in, const int* in_sizes, int n_in,
                              void* d_out, int out_size, void* d_ws, size_t ws_size,
                              hipStream_t stream) {
  const float* u     = (const float*)d_in[0];
  const float* lmap  = (const float*)d_in[1];
  const float* rw    = (const float*)d_in[2];
  const float* wdim  = (const float*)d_in[3];
  const float* bdim  = (const float*)d_in[4];
  const float* wpart = (const float*)d_in[5];
  const float* bpart = (const float*)d_in[6];
  float* out = (float*)d_out;

  // ---- workspace layout (bytes; ~85 MB total) ----
  char* W = (char*)d_ws;
  float* bl        = (float*)W;      W += 802816;     // [1000][200] f32
  _Float16* c1     = (_Float16*)W;   W += 458752;     // [1024][224]
  _Float16* c2     = (_Float16*)W;   W += 458752;
  _Float16* un1    = (_Float16*)W;   W += 6815744;    // [256][208][64]
  _Float16* un2    = (_Float16*)W;   W += 6815744;
  _Float16* ut1    = (_Float16*)W;   W += 7340032;    // [256][64][224]
  _Float16* ut2    = (_Float16*)W;   W += 7340032;
  unsigned short* h_bf16 = (unsigned short*)W; W += 524288;   // [256][1024]
  float* part      = (float*)W;      W += (size_t)NSLAB * SROW * SPL * 4;  // 54.5 MB
  // umap f32 (13.1 MB) overlaps part: dead after k_prep2, part written later.
  float* umap      = part;

  hipMemcpyAsync(bl, rw, (size_t)HCN_ * L_ * sizeof(float),
                 hipMemcpyDeviceToDevice, stream);
  k_umap<<<200, 256, 0, stream>>>(u, lmap, umap);
  k_prep2<<<256, 256, 0, stream>>>(umap, un1, un2, ut1, ut2);

  // t = 0: no partials yet
  k_softmax2<0><<<256, 256, 0, stream>>>(bl, part, c1, c2);
  k_iter<1, 0><<<512, 512, 0, stream>>>(c1, c2, un1, un2, ut1, ut2,
                                        wdim, bdim, part, h_bf16);
  // t = 1: fold in t=0 partials
  k_softmax2<1><<<256, 256, 0, stream>>>(bl, part, c1, c2);
  k_iter<1, 0><<<512, 512, 0, stream>>>(c1, c2, un1, un2, ut1, ut2,
                                        wdim, bdim, part, h_bf16);
  // t = 2: fold in t=1 partials; emit h, no UV
  k_softmax2<1><<<256, 256, 0, stream>>>(bl, part, c1, c2);
  k_iter<0, 1><<<512, 512, 0, stream>>>(c1, c2, un1, un2, ut1, ut2,
                                        wdim, bdim, part, h_bf16);

  k_out_mfma<<<dim3(157, 2), 512, 0, stream>>>(h_bf16, wpart, bpart, out);
}